// Round 10
// baseline (425.300 us; speedup 1.0000x reference)
//
#include <hip/hip_runtime.h>
#include <hip/hip_bf16.h>
#include <stdint.h>

// Problem constants (reference: N=20000, E=640000, C=D=M=128)
#define DIM 128
#define HSTR 136    // padded LDS row stride in bf16 elems (272 B, 16B-aligned rows)
#define NMAX 20224  // LDS-staged scan capacity

using bfrag = __attribute__((ext_vector_type(8))) short;   // 8 bf16 (4 VGPRs)
using f32x4 = __attribute__((ext_vector_type(4))) float;   // MFMA C/D

__device__ __forceinline__ float prelu_f(float v, float a) { return v >= 0.f ? v : a * v; }

// RNE bf16 (cold prep paths)
__device__ __forceinline__ unsigned short f2bf(float f) {
    unsigned u = __float_as_uint(f);
    unsigned r = (u + 0x7FFFu + ((u >> 16) & 1u)) >> 16;
    return (unsigned short)r;
}
// Hot path: round-half-up bf16, pack two -> u32 (a->lo16, b->hi16).
__device__ __forceinline__ unsigned pkbf(float a, float b) {
    const unsigned ua = __float_as_uint(a) + 0x8000u;
    const unsigned ub = __float_as_uint(b) + 0x8000u;
    return __builtin_amdgcn_perm(ub, ua, 0x07060302u);
}
__device__ __forceinline__ float bf_lo(unsigned u) { return __uint_as_float(u << 16); }
__device__ __forceinline__ float bf_hi(unsigned u) { return __uint_as_float(u & 0xFFFF0000u); }

// ---------------------------------------------------------------------------
// Merged prep + hist.
// ---------------------------------------------------------------------------
__global__ __launch_bounds__(256) void prep_hist_k(
    const float* __restrict__ Wsrc, const float* __restrict__ Wtgt,
    const float* __restrict__ Wskip, const float* __restrict__ W1,
    const float* __restrict__ W2, const float* __restrict__ b2,
    const float* __restrict__ Wg,
    unsigned short* __restrict__ Wall, float* __restrict__ w2g,
    const int* __restrict__ eidx, int E, int* __restrict__ deg)
{
    const int nhist = (E + 255) / 256;
    if ((int)blockIdx.x < nhist) {
        const int e = blockIdx.x * 256 + threadIdx.x;
        if (e < E) atomicAdd(deg + eidx[(size_t)E + e], 1);
        return;
    }
    const int b = blockIdx.x - nhist;
    if (b == (5 * DIM * DIM) / 256) {   // w2g block
        const int k = threadIdx.x;
        if (k < DIM) {
            float s = 0.f;
            for (int d = 0; d < DIM; ++d) s += W2[k * DIM + d] * Wg[d];
            w2g[k] = s;
        }
        return;
    }
    const int idx = b * 256 + threadIdx.x;
    const int m = idx >> 14;
    const int r = idx & 16383;
    const int n = r >> 7, k = r & 127;
    const float* W = (m == 0) ? Wsrc : (m == 1) ? Wtgt : (m == 2) ? Wskip : (m == 3) ? W1 : W2;
    Wall[idx] = f2bf(W[k * DIM + n]);
}

// ---------------------------------------------------------------------------
// Single-block scan, LDS-staged.
// ---------------------------------------------------------------------------
__global__ __launch_bounds__(256) void scan_k(const int* __restrict__ deg,
                                              int* __restrict__ rowptr,
                                              int* __restrict__ cursor, int N)
{
    __shared__ int part[256];
    const int t = threadIdx.x;

    if (N <= NMAX) {
        __shared__ int s[NMAX];
        for (int k = t; k < N; k += 256) s[k] = deg[k];
        __syncthreads();

        const int chunk = (N + 255) / 256;
        const int lo = min(t * chunk, N), hi = min(lo + chunk, N);
        int sum = 0;
        for (int k = lo; k < hi; ++k) sum += s[k];
        part[t] = sum;
        __syncthreads();
        for (int off = 1; off < 256; off <<= 1) {
            int u = (t >= off) ? part[t - off] : 0;
            __syncthreads();
            part[t] += u;
            __syncthreads();
        }
        int run = part[t] - sum;
        for (int k = lo; k < hi; ++k) { const int d = s[k]; s[k] = run; run += d; }
        __syncthreads();
        for (int k = t; k < N; k += 256) {
            const int v = s[k];
            rowptr[k] = v;
            cursor[k] = v;
        }
        if (t == 0) rowptr[N] = part[255];
    } else {
        const int chunk = (N + 255) / 256;
        const int lo = min(t * chunk, N), hi = min(lo + chunk, N);
        int s = 0;
        for (int k = lo; k < hi; ++k) s += deg[k];
        part[t] = s;
        __syncthreads();
        for (int off = 1; off < 256; off <<= 1) {
            int u = (t >= off) ? part[t - off] : 0;
            __syncthreads();
            part[t] += u;
            __syncthreads();
        }
        int run = part[t] - s;
        for (int k = lo; k < hi; ++k) {
            rowptr[k] = run;
            cursor[k] = run;
            run += deg[k];
        }
        if (t == 255) rowptr[N] = part[255];
    }
}

// ---------------------------------------------------------------------------
// Merged scatter + node_linear.
// ---------------------------------------------------------------------------
__global__ __launch_bounds__(256) void scatter_node_k(
    const int* __restrict__ eidx, int E, int* __restrict__ cursor,
    int2* __restrict__ jip, int nscatter,
    const float* __restrict__ x,
    const unsigned short* __restrict__ Wall,
    const float* __restrict__ bsrc,
    unsigned short* __restrict__ msg_src, unsigned short* __restrict__ msg_tgt,
    float* __restrict__ skip, int N)
{
    if ((int)blockIdx.x < nscatter) {
        const int e = blockIdx.x * 256 + threadIdx.x;
        if (e < E) {
            const int j = eidx[e];
            const int i = eidx[(size_t)E + e];
            const int p = atomicAdd(cursor + i, 1);
            jip[p] = make_int2(j, i);
        }
        return;
    }

    __shared__ unsigned short xt[32 * HSTR];
    const int t = threadIdx.x;
    const int n0blk = (blockIdx.x - nscatter) * 32;
    const int w = t >> 6, lane = t & 63, col = lane & 15, quad = lane >> 4;

    for (int k = t; k < 32 * 16; k += 256) {
        const int row = k >> 4, o = k & 15;
        uint4 v = make_uint4(0, 0, 0, 0);
        if (n0blk + row < N) {
            const float4 a = *(const float4*)(x + (size_t)(n0blk + row) * DIM + o * 8);
            const float4 b = *(const float4*)(x + (size_t)(n0blk + row) * DIM + o * 8 + 4);
            v.x = pkbf(a.x, a.y); v.y = pkbf(a.z, a.w);
            v.z = pkbf(b.x, b.y); v.w = pkbf(b.z, b.w);
        }
        *(uint4*)(xt + row * HSTR + o * 8) = v;
    }
    __syncthreads();

    bfrag af[2][4];
    #pragma unroll
    for (int mt = 0; mt < 2; ++mt)
        #pragma unroll
        for (int ks = 0; ks < 4; ++ks)
            af[mt][ks] = *(const bfrag*)(xt + (mt * 16 + col) * HSTR + ks * 32 + quad * 8);

    for (int m = 0; m < 3; ++m) {
        const unsigned short* Wt = Wall + m * DIM * DIM;
        bfrag bw[2][4];
        #pragma unroll
        for (int nt = 0; nt < 2; ++nt)
            #pragma unroll
            for (int ks = 0; ks < 4; ++ks)
                bw[nt][ks] = *(const bfrag*)(Wt + (w * 32 + nt * 16 + col) * DIM + ks * 32 + quad * 8);

        f32x4 acc[2][2];
        #pragma unroll
        for (int mt = 0; mt < 2; ++mt)
            #pragma unroll
            for (int nt = 0; nt < 2; ++nt)
                acc[mt][nt] = f32x4{0.f, 0.f, 0.f, 0.f};

        #pragma unroll
        for (int mt = 0; mt < 2; ++mt)
            #pragma unroll
            for (int nt = 0; nt < 2; ++nt)
                #pragma unroll
                for (int ks = 0; ks < 4; ++ks)
                    acc[mt][nt] = __builtin_amdgcn_mfma_f32_16x16x32_bf16(
                        bw[nt][ks], af[mt][ks], acc[mt][nt], 0, 0, 0);

        #pragma unroll
        for (int mt = 0; mt < 2; ++mt) {
            const int node = n0blk + mt * 16 + col;
            if (node >= N) continue;
            #pragma unroll
            for (int nt = 0; nt < 2; ++nt) {
                const int f0 = w * 32 + nt * 16 + quad * 4;
                if (m == 2) {
                    float4 o;
                    o.x = acc[mt][nt][0]; o.y = acc[mt][nt][1];
                    o.z = acc[mt][nt][2]; o.w = acc[mt][nt][3];
                    *(float4*)(skip + (size_t)node * DIM + f0) = o;
                } else {
                    float b0 = 0.f, b1v = 0.f, b2v = 0.f, b3v = 0.f;
                    if (m == 0) {
                        const float4 bb = *(const float4*)(bsrc + f0);
                        b0 = bb.x; b1v = bb.y; b2v = bb.z; b3v = bb.w;
                    }
                    uint2 o;
                    o.x = pkbf(acc[mt][nt][0] + b0, acc[mt][nt][1] + b1v);
                    o.y = pkbf(acc[mt][nt][2] + b2v, acc[mt][nt][3] + b3v);
                    unsigned short* dst = (m == 0) ? msg_src : msg_tgt;
                    *(uint2*)(dst + (size_t)node * DIM + f0) = o;
                }
            }
        }
    }
}

// ---------------------------------------------------------------------------
// K2: persistent fused edge GEMM1 + softmax-weighted segment aggregation.
// Non-transposed MFMA: D[edge][feature] (edge = mt*16+quad*4+r, feature =
// w*32+nt*16+col). Shift-free softmax (exp(g), clamp +60): per-node weights
// alpha cancel the shift exactly. Interior segments -> direct fp32 store of
// [sum exp(g)*h2, sum exp(g)]; boundary segments -> fp32 atomicAdd.
// aggf/sumexp must be zero-initialized.
// ---------------------------------------------------------------------------
__global__ __launch_bounds__(256, 3) void edge_fused_k(
    const int2* __restrict__ jip, int ntiles,
    const int* __restrict__ rowptr,
    const unsigned short* __restrict__ msg_src, const unsigned short* __restrict__ msg_tgt,
    const float* __restrict__ a0p,
    const unsigned short* __restrict__ W1t, const float* __restrict__ b1,
    const float* __restrict__ a1p,
    const float* __restrict__ w2g,
    float* __restrict__ aggf, float* __restrict__ sumexp)
{
    __shared__ unsigned short h1[2][64 * HSTR];
    __shared__ float gate_part[2][64][4];
    __shared__ int ii_l[2][64];

    const int t = threadIdx.x;
    const float a0 = *a0p, a1 = *a1p;
    const int w = t >> 6, lane = t & 63, col = lane & 15, quad = lane >> 4;
    const int o = t & 15, r0 = t >> 4;

    bfrag bw1[2][4];
    float b1v[2], w2gv[2];
    #pragma unroll
    for (int nt = 0; nt < 2; ++nt) {
        const int n = w * 32 + nt * 16 + col;
        #pragma unroll
        for (int ks = 0; ks < 4; ++ks)
            bw1[nt][ks] = *(const bfrag*)(W1t + n * DIM + ks * 32 + quad * 8);
        b1v[nt] = b1[n];
        w2gv[nt] = w2g[n];
    }
    const int stride = gridDim.x;

    int tile = blockIdx.x;
    if (tile >= ntiles) return;

    int2 eA[4], eB[4];
    uint4 svA[4], svB[4];

    {
        const int p0 = tile * 64;
        #pragma unroll
        for (int i = 0; i < 4; ++i) eA[i] = jip[p0 + r0 + 16 * i];
        #pragma unroll
        for (int i = 0; i < 4; ++i)
            svA[i] = *(const uint4*)(msg_src + (size_t)eA[i].x * DIM + o * 8);
        const int tn = tile + stride;
        const int p1 = (tn < ntiles ? tn : tile) * 64;
        #pragma unroll
        for (int i = 0; i < 4; ++i) eB[i] = jip[p1 + r0 + 16 * i];
    }

    int buf = 0;

    for (; tile < ntiles; tile += stride) {
        const int p0 = tile * 64;

        // 1. issue NEXT tile's random src loads
        #pragma unroll
        for (int i = 0; i < 4; ++i)
            svB[i] = *(const uint4*)(msg_src + (size_t)eB[i].x * DIM + o * 8);

        // 2. processing: tgt loads + combine + LDS write; node ids -> ii_l
        #pragma unroll
        for (int i = 0; i < 4; ++i) {
            if (o == 0) ii_l[buf][r0 + 16 * i] = eA[i].y;
            const uint4 gv = *(const uint4*)(msg_tgt + (size_t)eA[i].y * DIM + o * 8);
            uint4 hv;
            hv.x = pkbf(prelu_f(bf_lo(svA[i].x) + bf_lo(gv.x), a0),
                        prelu_f(bf_hi(svA[i].x) + bf_hi(gv.x), a0));
            hv.y = pkbf(prelu_f(bf_lo(svA[i].y) + bf_lo(gv.y), a0),
                        prelu_f(bf_hi(svA[i].y) + bf_hi(gv.y), a0));
            hv.z = pkbf(prelu_f(bf_lo(svA[i].z) + bf_lo(gv.z), a0),
                        prelu_f(bf_hi(svA[i].z) + bf_hi(gv.z), a0));
            hv.w = pkbf(prelu_f(bf_lo(svA[i].w) + bf_lo(gv.w), a0),
                        prelu_f(bf_hi(svA[i].w) + bf_hi(gv.w), a0));
            *(uint4*)(h1[buf] + (r0 + 16 * i) * HSTR + o * 8) = hv;
        }

        // 3. rotate idx; prefetch idx for tile+2*stride
        #pragma unroll
        for (int i = 0; i < 4; ++i) eA[i] = eB[i];
        {
            const int tnn = tile + 2 * stride;
            const int p2 = (tnn < ntiles ? tnn : tile) * 64;
            #pragma unroll
            for (int i = 0; i < 4; ++i) eB[i] = jip[p2 + r0 + 16 * i];
        }

        __syncthreads();   // barrier 1: h1[buf], ii_l[buf] ready

        // 4. GEMM1 non-transposed: D[edge][feature]
        f32x4 acc[4][2];
        #pragma unroll
        for (int mt = 0; mt < 4; ++mt)
            #pragma unroll
            for (int nt = 0; nt < 2; ++nt)
                acc[mt][nt] = f32x4{0.f, 0.f, 0.f, 0.f};

        #pragma unroll
        for (int mt = 0; mt < 4; ++mt) {
            bfrag af[4];
            #pragma unroll
            for (int ks = 0; ks < 4; ++ks)
                af[ks] = *(const bfrag*)(h1[buf] + (mt * 16 + col) * HSTR + ks * 32 + quad * 8);
            #pragma unroll
            for (int nt = 0; nt < 2; ++nt)
                #pragma unroll
                for (int ks = 0; ks < 4; ++ks)
                    acc[mt][nt] = __builtin_amdgcn_mfma_f32_16x16x32_bf16(
                        af[ks], bw1[nt][ks], acc[mt][nt], 0, 0, 0);
        }

        // 5. bias + prelu -> v ; gate partials (this wave's 32 features)
        float v[4][2][4];
        #pragma unroll
        for (int mt = 0; mt < 4; ++mt) {
            #pragma unroll
            for (int r = 0; r < 4; ++r) {
                #pragma unroll
                for (int nt = 0; nt < 2; ++nt)
                    v[mt][nt][r] = prelu_f(acc[mt][nt][r] + b1v[nt], a1);
                float gp = v[mt][0][r] * w2gv[0] + v[mt][1][r] * w2gv[1];
                gp += __shfl_xor(gp, 1);
                gp += __shfl_xor(gp, 2);
                gp += __shfl_xor(gp, 4);
                gp += __shfl_xor(gp, 8);
                if (col == 0) gate_part[buf][mt * 16 + quad * 4 + r][w] = gp;
            }
        }

        __syncthreads();   // barrier 2: gate_part[buf] complete

        // 6. full gates -> exp weights (per lane's 16 edge rows)
        float we[4][4];
        #pragma unroll
        for (int mt = 0; mt < 4; ++mt)
            #pragma unroll
            for (int r = 0; r < 4; ++r) {
                const float4 gp = *(const float4*)gate_part[buf][mt * 16 + quad * 4 + r];
                we[mt][r] = __expf(fminf(gp.x + gp.y + gp.z + gp.w, 60.f));
            }

        // 7. segment loop: masked in-lane sums + quad shfl; store/atomic
        int lo = 0;
        while (lo < 64) {
            const int node = ii_l[buf][lo];
            int hi = lo + 1;
            while (hi < 64 && ii_l[buf][hi] == node) ++hi;

            float s0 = 0.f, s1 = 0.f, se = 0.f;
            #pragma unroll
            for (int mt = 0; mt < 4; ++mt)
                #pragma unroll
                for (int r = 0; r < 4; ++r) {
                    const int m = mt * 16 + quad * 4 + r;
                    if (m >= lo && m < hi) {
                        const float e = we[mt][r];
                        se += e;
                        s0 += e * v[mt][0][r];
                        s1 += e * v[mt][1][r];
                    }
                }
            s0 += __shfl_xor(s0, 16); s0 += __shfl_xor(s0, 32);
            s1 += __shfl_xor(s1, 16); s1 += __shfl_xor(s1, 32);
            se += __shfl_xor(se, 16); se += __shfl_xor(se, 32);

            const int base = rowptr[node], end = rowptr[node + 1];
            const bool interior = (base == p0 + lo) && (end == p0 + hi);
            if (quad == 0) {
                float* dst = aggf + (size_t)node * DIM + w * 32 + col;
                if (interior) {
                    dst[0] = s0;
                    dst[16] = s1;
                } else {
                    atomicAdd(dst, s0);
                    atomicAdd(dst + 16, s1);
                }
                if (w == 0 && col == 0) {
                    if (interior) sumexp[node] = se;
                    else atomicAdd(sumexp + node, se);
                }
            }
            lo = hi;
        }

        // 8. rotate src buffer
        #pragma unroll
        for (int i = 0; i < 4; ++i) svA[i] = svB[i];
        buf ^= 1;
    }
}

// ---------------------------------------------------------------------------
// K4: out = LN((aggf/sumexp) @ W2 + b2 + skip) * gamma + beta, via bf16 MFMA.
// ---------------------------------------------------------------------------
__global__ __launch_bounds__(256) void node_out_k(
    const float* __restrict__ aggf, const float* __restrict__ sumexp,
    const unsigned short* __restrict__ W2t, const float* __restrict__ b2,
    const float* __restrict__ skip,
    const float* __restrict__ gamma, const float* __restrict__ beta,
    float* __restrict__ out, int N)
{
    __shared__ unsigned short hh[64 * HSTR];
    __shared__ float ls1[4][4][16], ls2[4][4][16];

    const int t = threadIdx.x;
    const int n0blk = blockIdx.x * 64;
    const int w = t >> 6, lane = t & 63, col = lane & 15, quad = lane >> 4;

    bfrag bw2[2][4];
    float4 b2q[2];
    #pragma unroll
    for (int nt = 0; nt < 2; ++nt) {
        const int n = w * 32 + nt * 16 + col;
        #pragma unroll
        for (int ks = 0; ks < 4; ++ks)
            bw2[nt][ks] = *(const bfrag*)(W2t + n * DIM + ks * 32 + quad * 8);
        b2q[nt] = *(const float4*)(b2 + w * 32 + nt * 16 + quad * 4);
    }

    for (int k = t; k < 64 * 16; k += 256) {
        const int row = k >> 4, o = k & 15;
        const int node = n0blk + row;
        uint4 vv = make_uint4(0, 0, 0, 0);
        if (node < N) {
            const float inv = 1.f / (sumexp[node] + 1e-16f);
            const float4 a = *(const float4*)(aggf + (size_t)node * DIM + o * 8);
            const float4 b = *(const float4*)(aggf + (size_t)node * DIM + o * 8 + 4);
            vv.x = pkbf(a.x * inv, a.y * inv);
            vv.y = pkbf(a.z * inv, a.w * inv);
            vv.z = pkbf(b.x * inv, b.y * inv);
            vv.w = pkbf(b.z * inv, b.w * inv);
        }
        *(uint4*)(hh + row * HSTR + o * 8) = vv;
    }
    __syncthreads();

    f32x4 acc[4][2];
    #pragma unroll
    for (int mt = 0; mt < 4; ++mt)
        #pragma unroll
        for (int nt = 0; nt < 2; ++nt)
            acc[mt][nt] = f32x4{0.f, 0.f, 0.f, 0.f};

    #pragma unroll
    for (int mt = 0; mt < 4; ++mt) {
        bfrag af[4];
        #pragma unroll
        for (int ks = 0; ks < 4; ++ks)
            af[ks] = *(const bfrag*)(hh + (mt * 16 + col) * HSTR + ks * 32 + quad * 8);
        #pragma unroll
        for (int nt = 0; nt < 2; ++nt)
            #pragma unroll
            for (int ks = 0; ks < 4; ++ks)
                acc[mt][nt] = __builtin_amdgcn_mfma_f32_16x16x32_bf16(
                    bw2[nt][ks], af[ks], acc[mt][nt], 0, 0, 0);
    }

    float v[4][2][4];
    #pragma unroll
    for (int mt = 0; mt < 4; ++mt) {
        const int node = n0blk + mt * 16 + col;
        float s1 = 0.f, s2 = 0.f;
        #pragma unroll
        for (int nt = 0; nt < 2; ++nt) {
            const int f0 = w * 32 + nt * 16 + quad * 4;
            float4 sk = make_float4(0.f, 0.f, 0.f, 0.f);
            if (node < N) sk = *(const float4*)(skip + (size_t)node * DIM + f0);
            v[mt][nt][0] = acc[mt][nt][0] + b2q[nt].x + sk.x;
            v[mt][nt][1] = acc[mt][nt][1] + b2q[nt].y + sk.y;
            v[mt][nt][2] = acc[mt][nt][2] + b2q[nt].z + sk.z;
            v[mt][nt][3] = acc[mt][nt][3] + b2q[nt].w + sk.w;
            #pragma unroll
            for (int r = 0; r < 4; ++r) {
                s1 += v[mt][nt][r];
                s2 += v[mt][nt][r] * v[mt][nt][r];
            }
        }
        s1 += __shfl_xor(s1, 16); s1 += __shfl_xor(s1, 32);
        s2 += __shfl_xor(s2, 16); s2 += __shfl_xor(s2, 32);
        if (quad == 0) { ls1[w][mt][col] = s1; ls2[w][mt][col] = s2; }
    }
    __syncthreads();

    #pragma unroll
    for (int mt = 0; mt < 4; ++mt) {
        const int node = n0blk + mt * 16 + col;
        if (node >= N) continue;
        const float sum = ls1[0][mt][col] + ls1[1][mt][col] + ls1[2][mt][col] + ls1[3][mt][col];
        const float sq  = ls2[0][mt][col] + ls2[1][mt][col] + ls2[2][mt][col] + ls2[3][mt][col];
        const float mu = sum * (1.f / 128.f);
        const float var = sq * (1.f / 128.f) - mu * mu;
        const float rs = rsqrtf(var + 1e-5f);
        #pragma unroll
        for (int nt = 0; nt < 2; ++nt) {
            const int f0 = w * 32 + nt * 16 + quad * 4;
            const float4 gm = *(const float4*)(gamma + f0);
            const float4 bt = *(const float4*)(beta + f0);
            float4 ov;
            ov.x = (v[mt][nt][0] - mu) * rs * gm.x + bt.x;
            ov.y = (v[mt][nt][1] - mu) * rs * gm.y + bt.y;
            ov.z = (v[mt][nt][2] - mu) * rs * gm.z + bt.z;
            ov.w = (v[mt][nt][3] - mu) * rs * gm.w + bt.w;
            *(float4*)(out + (size_t)node * DIM + f0) = ov;
        }
    }
}

// ---------------------------------------------------------------------------
extern "C" void kernel_launch(void* const* d_in, const int* in_sizes, int n_in,
                              void* d_out, int out_size, void* d_ws, size_t ws_size,
                              hipStream_t stream)
{
    const float* x     = (const float*)d_in[0];
    const int*   eidx  = (const int*)d_in[1];
    const float* Wsrc  = (const float*)d_in[2];
    const float* bsrc  = (const float*)d_in[3];
    const float* Wtgt  = (const float*)d_in[4];
    const float* Wskip = (const float*)d_in[5];
    const float* a0    = (const float*)d_in[6];
    const float* W1    = (const float*)d_in[7];
    const float* b1    = (const float*)d_in[8];
    const float* a1    = (const float*)d_in[9];
    const float* W2    = (const float*)d_in[10];
    const float* b2    = (const float*)d_in[11];
    const float* Wg    = (const float*)d_in[12];
    const float* gamma = (const float*)d_in[13];
    const float* beta  = (const float*)d_in[14];

    const int N = in_sizes[0] / DIM;      // 20000
    const int E = in_sizes[1] / 2;        // 640000
    const int Npad = ((N + 63) / 64) * 64;
    float* out = (float*)d_out;

    char* ws = (char*)d_ws;
    size_t off = 0;
    auto alloc = [&](size_t bytes) -> void* {
        void* p = ws + off;
        off += (bytes + 255) & ~(size_t)255;
        return p;
    };
    unsigned short* msg_src = (unsigned short*)alloc((size_t)N * DIM * 2);
    unsigned short* msg_tgt = (unsigned short*)alloc((size_t)N * DIM * 2);
    float*          skip    = (float*)alloc((size_t)N * DIM * 4);
    // zero region: deg + sumexp + aggf (contiguous)
    int*            deg     = (int*)alloc((size_t)N * 4);
    float*          sumexp  = (float*)alloc((size_t)N * 4);
    float*          aggf    = (float*)alloc((size_t)N * DIM * 4);
    int*            rowptr  = (int*)alloc((size_t)(N + 1) * 4);
    int*            cursor  = (int*)alloc((size_t)N * 4);
    int2*           jip     = (int2*)alloc((size_t)E * 8);
    unsigned short* Wall    = (unsigned short*)alloc((size_t)5 * DIM * DIM * 2);
    float*          w2g     = (float*)alloc((size_t)(DIM + 1) * 4);
    (void)ws_size; (void)n_in; (void)out_size;

    const size_t zbytes = (size_t)((char*)aggf - (char*)deg) + (size_t)N * DIM * 4;
    hipMemsetAsync(deg, 0, zbytes, stream);

    const int nhist = (E + 255) / 256;
    prep_hist_k<<<nhist + (5 * DIM * DIM) / 256 + 1, 256, 0, stream>>>(
        Wsrc, Wtgt, Wskip, W1, W2, b2, Wg, Wall, w2g, eidx, E, deg);

    scan_k<<<1, 256, 0, stream>>>(deg, rowptr, cursor, N);

    const int nscatter = (E + 255) / 256;
    const int nnode = (N + 31) / 32;
    scatter_node_k<<<nscatter + nnode, 256, 0, stream>>>(
        eidx, E, cursor, jip, nscatter,
        x, Wall, bsrc, msg_src, msg_tgt, skip, N);

    const int ntiles = E / 64;
    const int egrid = ntiles < 1024 ? ntiles : 1024;
    edge_fused_k<<<egrid, 256, 0, stream>>>(jip, ntiles, rowptr, msg_src, msg_tgt, a0,
                                            Wall + 3 * DIM * DIM, b1, a1,
                                            w2g, aggf, sumexp);

    node_out_k<<<Npad / 64, 256, 0, stream>>>(aggf, sumexp, Wall + 4 * DIM * DIM, b2, skip,
                                              gamma, beta, out, N);
}

// Round 11
// 332.409 us; speedup vs baseline: 1.2794x; 1.2794x over previous
//
#include <hip/hip_runtime.h>
#include <hip/hip_bf16.h>
#include <stdint.h>

// Problem constants (reference: N=20000, E=640000, C=D=M=128)
#define DIM 128
#define HSTR 136    // padded LDS row stride in bf16 elems (272 B, 16B-aligned rows)
#define NMAX 20224  // LDS-staged scan capacity

using bfrag = __attribute__((ext_vector_type(8))) short;   // 8 bf16 (4 VGPRs)
using f32x4 = __attribute__((ext_vector_type(4))) float;   // MFMA C/D

__device__ __forceinline__ float prelu_f(float v, float a) { return v >= 0.f ? v : a * v; }

// RNE bf16 (cold prep paths)
__device__ __forceinline__ unsigned short f2bf(float f) {
    unsigned u = __float_as_uint(f);
    unsigned r = (u + 0x7FFFu + ((u >> 16) & 1u)) >> 16;
    return (unsigned short)r;
}
// Hot path: round-half-up bf16, pack two -> u32 (a->lo16, b->hi16).
__device__ __forceinline__ unsigned pkbf(float a, float b) {
    const unsigned ua = __float_as_uint(a) + 0x8000u;
    const unsigned ub = __float_as_uint(b) + 0x8000u;
    return __builtin_amdgcn_perm(ub, ua, 0x07060302u);
}
__device__ __forceinline__ float bf_lo(unsigned u) { return __uint_as_float(u << 16); }
__device__ __forceinline__ float bf_hi(unsigned u) { return __uint_as_float(u & 0xFFFF0000u); }

// ---------------------------------------------------------------------------
// Merged prep + hist.
// ---------------------------------------------------------------------------
__global__ __launch_bounds__(256) void prep_hist_k(
    const float* __restrict__ Wsrc, const float* __restrict__ Wtgt,
    const float* __restrict__ Wskip, const float* __restrict__ W1,
    const float* __restrict__ W2, const float* __restrict__ b2,
    const float* __restrict__ Wg,
    unsigned short* __restrict__ Wall, float* __restrict__ w2g,
    const int* __restrict__ eidx, int E, int* __restrict__ deg)
{
    const int nhist = (E + 255) / 256;
    if ((int)blockIdx.x < nhist) {
        const int e = blockIdx.x * 256 + threadIdx.x;
        if (e < E) atomicAdd(deg + eidx[(size_t)E + e], 1);
        return;
    }
    const int b = blockIdx.x - nhist;
    if (b == (5 * DIM * DIM) / 256) {   // w2g block
        const int k = threadIdx.x;
        if (k < DIM) {
            float s = 0.f;
            for (int d = 0; d < DIM; ++d) s += W2[k * DIM + d] * Wg[d];
            w2g[k] = s;
        } else if (k == DIM) {
            float s = 0.f;
            for (int d = 0; d < DIM; ++d) s += b2[d] * Wg[d];
            w2g[DIM] = s;
        }
        return;
    }
    const int idx = b * 256 + threadIdx.x;
    const int m = idx >> 14;
    const int r = idx & 16383;
    const int n = r >> 7, k = r & 127;
    const float* W = (m == 0) ? Wsrc : (m == 1) ? Wtgt : (m == 2) ? Wskip : (m == 3) ? W1 : W2;
    Wall[idx] = f2bf(W[k * DIM + n]);
}

// ---------------------------------------------------------------------------
// Single-block scan, LDS-staged.
// ---------------------------------------------------------------------------
__global__ __launch_bounds__(256) void scan_k(const int* __restrict__ deg,
                                              int* __restrict__ rowptr,
                                              int* __restrict__ cursor, int N)
{
    __shared__ int part[256];
    const int t = threadIdx.x;

    if (N <= NMAX) {
        __shared__ int s[NMAX];
        for (int k = t; k < N; k += 256) s[k] = deg[k];
        __syncthreads();

        const int chunk = (N + 255) / 256;
        const int lo = min(t * chunk, N), hi = min(lo + chunk, N);
        int sum = 0;
        for (int k = lo; k < hi; ++k) sum += s[k];
        part[t] = sum;
        __syncthreads();
        for (int off = 1; off < 256; off <<= 1) {
            int u = (t >= off) ? part[t - off] : 0;
            __syncthreads();
            part[t] += u;
            __syncthreads();
        }
        int run = part[t] - sum;
        for (int k = lo; k < hi; ++k) { const int d = s[k]; s[k] = run; run += d; }
        __syncthreads();
        for (int k = t; k < N; k += 256) {
            const int v = s[k];
            rowptr[k] = v;
            cursor[k] = v;
        }
        if (t == 0) rowptr[N] = part[255];
    } else {
        const int chunk = (N + 255) / 256;
        const int lo = min(t * chunk, N), hi = min(lo + chunk, N);
        int s = 0;
        for (int k = lo; k < hi; ++k) s += deg[k];
        part[t] = s;
        __syncthreads();
        for (int off = 1; off < 256; off <<= 1) {
            int u = (t >= off) ? part[t - off] : 0;
            __syncthreads();
            part[t] += u;
            __syncthreads();
        }
        int run = part[t] - s;
        for (int k = lo; k < hi; ++k) {
            rowptr[k] = run;
            cursor[k] = run;
            run += deg[k];
        }
        if (t == 255) rowptr[N] = part[255];
    }
}

// ---------------------------------------------------------------------------
// Merged scatter + node_linear.
// ---------------------------------------------------------------------------
__global__ __launch_bounds__(256) void scatter_node_k(
    const int* __restrict__ eidx, int E, int* __restrict__ cursor,
    int2* __restrict__ jip, int nscatter,
    const float* __restrict__ x,
    const unsigned short* __restrict__ Wall,
    const float* __restrict__ bsrc,
    unsigned short* __restrict__ msg_src, unsigned short* __restrict__ msg_tgt,
    float* __restrict__ skip, int N)
{
    if ((int)blockIdx.x < nscatter) {
        const int e = blockIdx.x * 256 + threadIdx.x;
        if (e < E) {
            const int j = eidx[e];
            const int i = eidx[(size_t)E + e];
            const int p = atomicAdd(cursor + i, 1);
            jip[p] = make_int2(j, i);
        }
        return;
    }

    __shared__ unsigned short xt[32 * HSTR];
    const int t = threadIdx.x;
    const int n0blk = (blockIdx.x - nscatter) * 32;
    const int w = t >> 6, lane = t & 63, col = lane & 15, quad = lane >> 4;

    for (int k = t; k < 32 * 16; k += 256) {
        const int row = k >> 4, o = k & 15;
        uint4 v = make_uint4(0, 0, 0, 0);
        if (n0blk + row < N) {
            const float4 a = *(const float4*)(x + (size_t)(n0blk + row) * DIM + o * 8);
            const float4 b = *(const float4*)(x + (size_t)(n0blk + row) * DIM + o * 8 + 4);
            v.x = pkbf(a.x, a.y); v.y = pkbf(a.z, a.w);
            v.z = pkbf(b.x, b.y); v.w = pkbf(b.z, b.w);
        }
        *(uint4*)(xt + row * HSTR + o * 8) = v;
    }
    __syncthreads();

    bfrag af[2][4];
    #pragma unroll
    for (int mt = 0; mt < 2; ++mt)
        #pragma unroll
        for (int ks = 0; ks < 4; ++ks)
            af[mt][ks] = *(const bfrag*)(xt + (mt * 16 + col) * HSTR + ks * 32 + quad * 8);

    for (int m = 0; m < 3; ++m) {
        const unsigned short* Wt = Wall + m * DIM * DIM;
        bfrag bw[2][4];
        #pragma unroll
        for (int nt = 0; nt < 2; ++nt)
            #pragma unroll
            for (int ks = 0; ks < 4; ++ks)
                bw[nt][ks] = *(const bfrag*)(Wt + (w * 32 + nt * 16 + col) * DIM + ks * 32 + quad * 8);

        f32x4 acc[2][2];
        #pragma unroll
        for (int mt = 0; mt < 2; ++mt)
            #pragma unroll
            for (int nt = 0; nt < 2; ++nt)
                acc[mt][nt] = f32x4{0.f, 0.f, 0.f, 0.f};

        #pragma unroll
        for (int mt = 0; mt < 2; ++mt)
            #pragma unroll
            for (int nt = 0; nt < 2; ++nt)
                #pragma unroll
                for (int ks = 0; ks < 4; ++ks)
                    acc[mt][nt] = __builtin_amdgcn_mfma_f32_16x16x32_bf16(
                        bw[nt][ks], af[mt][ks], acc[mt][nt], 0, 0, 0);

        #pragma unroll
        for (int mt = 0; mt < 2; ++mt) {
            const int node = n0blk + mt * 16 + col;
            if (node >= N) continue;
            #pragma unroll
            for (int nt = 0; nt < 2; ++nt) {
                const int f0 = w * 32 + nt * 16 + quad * 4;
                if (m == 2) {
                    float4 o;
                    o.x = acc[mt][nt][0]; o.y = acc[mt][nt][1];
                    o.z = acc[mt][nt][2]; o.w = acc[mt][nt][3];
                    *(float4*)(skip + (size_t)node * DIM + f0) = o;
                } else {
                    float b0 = 0.f, b1v = 0.f, b2v = 0.f, b3v = 0.f;
                    if (m == 0) {
                        const float4 bb = *(const float4*)(bsrc + f0);
                        b0 = bb.x; b1v = bb.y; b2v = bb.z; b3v = bb.w;
                    }
                    uint2 o;
                    o.x = pkbf(acc[mt][nt][0] + b0, acc[mt][nt][1] + b1v);
                    o.y = pkbf(acc[mt][nt][2] + b2v, acc[mt][nt][3] + b3v);
                    unsigned short* dst = (m == 0) ? msg_src : msg_tgt;
                    *(uint2*)(dst + (size_t)node * DIM + f0) = o;
                }
            }
        }
    }
}

// ---------------------------------------------------------------------------
// K2: persistent, software-pipelined per-edge GEMM1 + gate (R9-proven).
// ---------------------------------------------------------------------------
__global__ __launch_bounds__(256, 3) void edge_mlp_mfma(
    const int2* __restrict__ jip, int ntiles,
    const unsigned short* __restrict__ msg_src, const unsigned short* __restrict__ msg_tgt,
    const float* __restrict__ a0p,
    const unsigned short* __restrict__ W1t, const float* __restrict__ b1,
    const float* __restrict__ a1p,
    const float* __restrict__ w2g,
    unsigned short* __restrict__ h2buf,
    float* __restrict__ gate)
{
    __shared__ unsigned short h1[2][64 * HSTR];
    __shared__ float gate_part[2][4][64];

    const int t = threadIdx.x;
    const float a0 = *a0p, a1 = *a1p;
    const int w = t >> 6, lane = t & 63, col = lane & 15, quad = lane >> 4;
    const int o = t & 15, r0 = t >> 4;

    bfrag bw1[2][4];
    float4 b1q[2], wgq[2];
    #pragma unroll
    for (int nt = 0; nt < 2; ++nt) {
        const int n = w * 32 + nt * 16 + col;
        #pragma unroll
        for (int ks = 0; ks < 4; ++ks)
            bw1[nt][ks] = *(const bfrag*)(W1t + n * DIM + ks * 32 + quad * 8);
        const int nq = w * 32 + nt * 16 + quad * 4;
        b1q[nt] = *(const float4*)(b1 + nq);
        wgq[nt] = *(const float4*)(w2g + nq);
    }
    const float c2 = w2g[DIM];
    const int stride = gridDim.x;

    int tile = blockIdx.x;
    if (tile >= ntiles) return;

    int2 eA[4], eB[4];
    uint4 svA[4], svB[4];

    {
        const int p0 = tile * 64;
        #pragma unroll
        for (int i = 0; i < 4; ++i) eA[i] = jip[p0 + r0 + 16 * i];
        #pragma unroll
        for (int i = 0; i < 4; ++i)
            svA[i] = *(const uint4*)(msg_src + (size_t)eA[i].x * DIM + o * 8);
        const int tn = tile + stride;
        const int p1 = (tn < ntiles ? tn : tile) * 64;
        #pragma unroll
        for (int i = 0; i < 4; ++i) eB[i] = jip[p1 + r0 + 16 * i];
    }

    int buf = 0;
    int prev_p0 = -1;

    for (; tile < ntiles; tile += stride) {
        const int p0 = tile * 64;

        // 1. issue NEXT tile's random src loads
        #pragma unroll
        for (int i = 0; i < 4; ++i)
            svB[i] = *(const uint4*)(msg_src + (size_t)eB[i].x * DIM + o * 8);

        // 2. processing: tgt loads (L2-hot) + combine + LDS write
        #pragma unroll
        for (int i = 0; i < 4; ++i) {
            const uint4 gv = *(const uint4*)(msg_tgt + (size_t)eA[i].y * DIM + o * 8);
            uint4 hv;
            hv.x = pkbf(prelu_f(bf_lo(svA[i].x) + bf_lo(gv.x), a0),
                        prelu_f(bf_hi(svA[i].x) + bf_hi(gv.x), a0));
            hv.y = pkbf(prelu_f(bf_lo(svA[i].y) + bf_lo(gv.y), a0),
                        prelu_f(bf_hi(svA[i].y) + bf_hi(gv.y), a0));
            hv.z = pkbf(prelu_f(bf_lo(svA[i].z) + bf_lo(gv.z), a0),
                        prelu_f(bf_hi(svA[i].z) + bf_hi(gv.z), a0));
            hv.w = pkbf(prelu_f(bf_lo(svA[i].w) + bf_lo(gv.w), a0),
                        prelu_f(bf_hi(svA[i].w) + bf_hi(gv.w), a0));
            *(uint4*)(h1[buf] + (r0 + 16 * i) * HSTR + o * 8) = hv;
        }

        // 3. rotate idx; prefetch idx for tile+2*stride
        #pragma unroll
        for (int i = 0; i < 4; ++i) eA[i] = eB[i];
        {
            const int tnn = tile + 2 * stride;
            const int p2 = (tnn < ntiles ? tnn : tile) * 64;
            #pragma unroll
            for (int i = 0; i < 4; ++i) eB[i] = jip[p2 + r0 + 16 * i];
        }

        __syncthreads();

        // 3b. deferred gate write for PREVIOUS tile
        if (prev_p0 >= 0 && t < 64)
            gate[prev_p0 + t] = gate_part[1 - buf][0][t] + gate_part[1 - buf][1][t]
                              + gate_part[1 - buf][2][t] + gate_part[1 - buf][3][t] + c2;

        // 4. GEMM1 (transposed)
        f32x4 acc[4][2];
        #pragma unroll
        for (int mt = 0; mt < 4; ++mt)
            #pragma unroll
            for (int nt = 0; nt < 2; ++nt)
                acc[mt][nt] = f32x4{0.f, 0.f, 0.f, 0.f};

        #pragma unroll
        for (int mt = 0; mt < 4; ++mt) {
            bfrag af[4];
            #pragma unroll
            for (int ks = 0; ks < 4; ++ks)
                af[ks] = *(const bfrag*)(h1[buf] + (mt * 16 + col) * HSTR + ks * 32 + quad * 8);
            #pragma unroll
            for (int nt = 0; nt < 2; ++nt)
                #pragma unroll
                for (int ks = 0; ks < 4; ++ks)
                    acc[mt][nt] = __builtin_amdgcn_mfma_f32_16x16x32_bf16(
                        bw1[nt][ks], af[ks], acc[mt][nt], 0, 0, 0);
        }

        // 5. epilogue: prelu -> h2buf, gate partials
        #pragma unroll
        for (int mt = 0; mt < 4; ++mt) {
            const int m = mt * 16 + col;
            float g = 0.f;
            #pragma unroll
            for (int nt = 0; nt < 2; ++nt) {
                const int n0 = w * 32 + nt * 16 + quad * 4;
                const float p0v = prelu_f(acc[mt][nt][0] + b1q[nt].x, a1);
                const float p1v = prelu_f(acc[mt][nt][1] + b1q[nt].y, a1);
                const float p2v = prelu_f(acc[mt][nt][2] + b1q[nt].z, a1);
                const float p3v = prelu_f(acc[mt][nt][3] + b1q[nt].w, a1);
                uint2 ov;
                ov.x = pkbf(p0v, p1v);
                ov.y = pkbf(p2v, p3v);
                *(uint2*)(h2buf + (size_t)(p0 + m) * DIM + n0) = ov;
                g += p0v * wgq[nt].x + p1v * wgq[nt].y + p2v * wgq[nt].z + p3v * wgq[nt].w;
            }
            g += __shfl_xor(g, 16);
            g += __shfl_xor(g, 32);
            if (quad == 0) gate_part[buf][w][m] = g;
        }

        #pragma unroll
        for (int i = 0; i < 4; ++i) svA[i] = svB[i];
        prev_p0 = p0;
        buf ^= 1;
    }

    __syncthreads();
    if (t < 64)
        gate[prev_p0 + t] = gate_part[1 - buf][0][t] + gate_part[1 - buf][1][t]
                          + gate_part[1 - buf][2][t] + gate_part[1 - buf][3][t] + c2;
}

// ---------------------------------------------------------------------------
// K3: merged softmax-aggregate + W2-GEMM + skip + LN. 64 nodes/block.
// Phase 1: each wave aggregates 16 nodes (shift-free softmax: weights
// exp(min(g,60)); normalization cancels the shift exactly) -> bf16 rows in LDS.
// Phase 2: MFMA with W2, + b2 + skip, LayerNorm, store.
// ---------------------------------------------------------------------------
__global__ __launch_bounds__(256) void node_final_k(
    const int* __restrict__ rowptr,
    const float* __restrict__ gate, const unsigned short* __restrict__ h2buf,
    const unsigned short* __restrict__ W2t, const float* __restrict__ b2,
    const float* __restrict__ skip,
    const float* __restrict__ gamma, const float* __restrict__ beta,
    float* __restrict__ out, int N)
{
    __shared__ unsigned short hh[64 * HSTR];
    __shared__ float ls1[4][4][16], ls2[4][4][16];

    const int t = threadIdx.x;
    const int n0blk = blockIdx.x * 64;
    const int w = t >> 6, lane = t & 63, col = lane & 15, quad = lane >> 4;
    const int grp = lane >> 4, sub = lane & 15;

    // W2 fragments load overlaps phase-1 memory work
    bfrag bw2[2][4];
    float4 b2q[2];
    #pragma unroll
    for (int nt = 0; nt < 2; ++nt) {
        const int n = w * 32 + nt * 16 + col;
        #pragma unroll
        for (int ks = 0; ks < 4; ++ks)
            bw2[nt][ks] = *(const bfrag*)(W2t + n * DIM + ks * 32 + quad * 8);
        b2q[nt] = *(const float4*)(b2 + w * 32 + nt * 16 + quad * 4);
    }

    // Phase 1: wave w aggregates nodes n0blk + w*16 + idx
    for (int idx = 0; idx < 16; ++idx) {
        const int n = n0blk + w * 16 + idx;
        const int row = w * 16 + idx;
        if (n >= N) {
            if (grp == 0) {
                uint4 z = make_uint4(0, 0, 0, 0);
                *(uint4*)(hh + row * HSTR + sub * 8) = z;
            }
            continue;
        }
        const int base = rowptr[n];
        const int deg = rowptr[n + 1] - base;

        float acc[8] = {0.f, 0.f, 0.f, 0.f, 0.f, 0.f, 0.f, 0.f};
        float se = 0.f;
        for (int k = grp; k < deg; k += 4) {
            const float e = __expf(fminf(gate[base + k], 60.f));
            se += e;
            const uint4 mv = *(const uint4*)(h2buf + (size_t)(base + k) * DIM + sub * 8);
            acc[0] += e * bf_lo(mv.x); acc[1] += e * bf_hi(mv.x);
            acc[2] += e * bf_lo(mv.y); acc[3] += e * bf_hi(mv.y);
            acc[4] += e * bf_lo(mv.z); acc[5] += e * bf_hi(mv.z);
            acc[6] += e * bf_lo(mv.w); acc[7] += e * bf_hi(mv.w);
        }
        #pragma unroll
        for (int j = 0; j < 8; ++j) {
            acc[j] += __shfl_xor(acc[j], 16);
            acc[j] += __shfl_xor(acc[j], 32);
        }
        se += __shfl_xor(se, 16);
        se += __shfl_xor(se, 32);
        const float inv = 1.f / (se + 1e-16f);

        if (grp == 0) {
            uint4 ov;
            ov.x = pkbf(acc[0] * inv, acc[1] * inv);
            ov.y = pkbf(acc[2] * inv, acc[3] * inv);
            ov.z = pkbf(acc[4] * inv, acc[5] * inv);
            ov.w = pkbf(acc[6] * inv, acc[7] * inv);
            *(uint4*)(hh + row * HSTR + sub * 8) = ov;
        }
    }
    __syncthreads();

    // Phase 2: GEMM with W2 (transposed: D[feature][node]) + skip + LN
    f32x4 acc[4][2];
    #pragma unroll
    for (int mt = 0; mt < 4; ++mt)
        #pragma unroll
        for (int nt = 0; nt < 2; ++nt)
            acc[mt][nt] = f32x4{0.f, 0.f, 0.f, 0.f};

    #pragma unroll
    for (int mt = 0; mt < 4; ++mt) {
        bfrag af[4];
        #pragma unroll
        for (int ks = 0; ks < 4; ++ks)
            af[ks] = *(const bfrag*)(hh + (mt * 16 + col) * HSTR + ks * 32 + quad * 8);
        #pragma unroll
        for (int nt = 0; nt < 2; ++nt)
            #pragma unroll
            for (int ks = 0; ks < 4; ++ks)
                acc[mt][nt] = __builtin_amdgcn_mfma_f32_16x16x32_bf16(
                    bw2[nt][ks], af[ks], acc[mt][nt], 0, 0, 0);
    }

    float v[4][2][4];
    #pragma unroll
    for (int mt = 0; mt < 4; ++mt) {
        const int node = n0blk + mt * 16 + col;
        float s1 = 0.f, s2 = 0.f;
        #pragma unroll
        for (int nt = 0; nt < 2; ++nt) {
            const int f0 = w * 32 + nt * 16 + quad * 4;
            float4 sk = make_float4(0.f, 0.f, 0.f, 0.f);
            if (node < N) sk = *(const float4*)(skip + (size_t)node * DIM + f0);
            v[mt][nt][0] = acc[mt][nt][0] + b2q[nt].x + sk.x;
            v[mt][nt][1] = acc[mt][nt][1] + b2q[nt].y + sk.y;
            v[mt][nt][2] = acc[mt][nt][2] + b2q[nt].z + sk.z;
            v[mt][nt][3] = acc[mt][nt][3] + b2q[nt].w + sk.w;
            #pragma unroll
            for (int r = 0; r < 4; ++r) {
                s1 += v[mt][nt][r];
                s2 += v[mt][nt][r] * v[mt][nt][r];
            }
        }
        s1 += __shfl_xor(s1, 16); s1 += __shfl_xor(s1, 32);
        s2 += __shfl_xor(s2, 16); s2 += __shfl_xor(s2, 32);
        if (quad == 0) { ls1[w][mt][col] = s1; ls2[w][mt][col] = s2; }
    }
    __syncthreads();

    #pragma unroll
    for (int mt = 0; mt < 4; ++mt) {
        const int node = n0blk + mt * 16 + col;
        if (node >= N) continue;
        const float sum = ls1[0][mt][col] + ls1[1][mt][col] + ls1[2][mt][col] + ls1[3][mt][col];
        const float sq  = ls2[0][mt][col] + ls2[1][mt][col] + ls2[2][mt][col] + ls2[3][mt][col];
        const float mu = sum * (1.f / 128.f);
        const float var = sq * (1.f / 128.f) - mu * mu;
        const float rs = rsqrtf(var + 1e-5f);
        #pragma unroll
        for (int nt = 0; nt < 2; ++nt) {
            const int f0 = w * 32 + nt * 16 + quad * 4;
            const float4 gm = *(const float4*)(gamma + f0);
            const float4 bt = *(const float4*)(beta + f0);
            float4 ov;
            ov.x = (v[mt][nt][0] - mu) * rs * gm.x + bt.x;
            ov.y = (v[mt][nt][1] - mu) * rs * gm.y + bt.y;
            ov.z = (v[mt][nt][2] - mu) * rs * gm.z + bt.z;
            ov.w = (v[mt][nt][3] - mu) * rs * gm.w + bt.w;
            *(float4*)(out + (size_t)node * DIM + f0) = ov;
        }
    }
}

// ---------------------------------------------------------------------------
extern "C" void kernel_launch(void* const* d_in, const int* in_sizes, int n_in,
                              void* d_out, int out_size, void* d_ws, size_t ws_size,
                              hipStream_t stream)
{
    const float* x     = (const float*)d_in[0];
    const int*   eidx  = (const int*)d_in[1];
    const float* Wsrc  = (const float*)d_in[2];
    const float* bsrc  = (const float*)d_in[3];
    const float* Wtgt  = (const float*)d_in[4];
    const float* Wskip = (const float*)d_in[5];
    const float* a0    = (const float*)d_in[6];
    const float* W1    = (const float*)d_in[7];
    const float* b1    = (const float*)d_in[8];
    const float* a1    = (const float*)d_in[9];
    const float* W2    = (const float*)d_in[10];
    const float* b2    = (const float*)d_in[11];
    const float* Wg    = (const float*)d_in[12];
    const float* gamma = (const float*)d_in[13];
    const float* beta  = (const float*)d_in[14];

    const int N = in_sizes[0] / DIM;      // 20000
    const int E = in_sizes[1] / 2;        // 640000
    const int Npad = ((N + 63) / 64) * 64;
    float* out = (float*)d_out;

    char* ws = (char*)d_ws;
    size_t off = 0;
    auto alloc = [&](size_t bytes) -> void* {
        void* p = ws + off;
        off += (bytes + 255) & ~(size_t)255;
        return p;
    };
    unsigned short* msg_src = (unsigned short*)alloc((size_t)N * DIM * 2);
    unsigned short* msg_tgt = (unsigned short*)alloc((size_t)N * DIM * 2);
    float*          skip    = (float*)alloc((size_t)N * DIM * 4);
    float*          gate    = (float*)alloc((size_t)E * 4);
    int*            deg     = (int*)alloc((size_t)N * 4);
    int*            rowptr  = (int*)alloc((size_t)(N + 1) * 4);
    int*            cursor  = (int*)alloc((size_t)N * 4);
    int2*           jip     = (int2*)alloc((size_t)E * 8);
    unsigned short* Wall    = (unsigned short*)alloc((size_t)5 * DIM * DIM * 2);
    float*          w2g     = (float*)alloc((size_t)(DIM + 1) * 4);
    unsigned short* h2buf   = (unsigned short*)alloc((size_t)E * DIM * 2);
    (void)ws_size; (void)n_in; (void)out_size;

    hipMemsetAsync(deg, 0, (size_t)N * 4, stream);

    const int nhist = (E + 255) / 256;
    prep_hist_k<<<nhist + (5 * DIM * DIM) / 256 + 1, 256, 0, stream>>>(
        Wsrc, Wtgt, Wskip, W1, W2, b2, Wg, Wall, w2g, eidx, E, deg);

    scan_k<<<1, 256, 0, stream>>>(deg, rowptr, cursor, N);

    const int nscatter = (E + 255) / 256;
    const int nnode = (N + 31) / 32;
    scatter_node_k<<<nscatter + nnode, 256, 0, stream>>>(
        eidx, E, cursor, jip, nscatter,
        x, Wall, bsrc, msg_src, msg_tgt, skip, N);

    const int ntiles = E / 64;
    const int egrid = ntiles < 1024 ? ntiles : 1024;
    edge_mlp_mfma<<<egrid, 256, 0, stream>>>(jip, ntiles, msg_src, msg_tgt, a0,
                                             Wall + 3 * DIM * DIM, b1, a1,
                                             w2g, h2buf, gate);

    node_final_k<<<Npad / 64, 256, 0, stream>>>(rowptr, gate, h2buf,
                                                Wall + 4 * DIM * DIM, b2, skip,
                                                gamma, beta, out, N);
}

// Round 12
// 294.251 us; speedup vs baseline: 1.4454x; 1.1297x over previous
//
#include <hip/hip_runtime.h>
#include <hip/hip_bf16.h>
#include <stdint.h>

// Problem constants (reference: N=20000, E=640000, C=D=M=128)
#define DIM 128
#define HSTR 136    // padded LDS row stride in bf16 elems (272 B, 16B-aligned rows)
#define NMAX 20224  // LDS-staged scan capacity

using bfrag = __attribute__((ext_vector_type(8))) short;   // 8 bf16 (4 VGPRs)
using f32x4 = __attribute__((ext_vector_type(4))) float;   // MFMA C/D

__device__ __forceinline__ float prelu_f(float v, float a) { return v >= 0.f ? v : a * v; }

// RNE bf16 (cold prep paths)
__device__ __forceinline__ unsigned short f2bf(float f) {
    unsigned u = __float_as_uint(f);
    unsigned r = (u + 0x7FFFu + ((u >> 16) & 1u)) >> 16;
    return (unsigned short)r;
}
// Hot path: round-half-up bf16, pack two -> u32 (a->lo16, b->hi16).
__device__ __forceinline__ unsigned pkbf(float a, float b) {
    const unsigned ua = __float_as_uint(a) + 0x8000u;
    const unsigned ub = __float_as_uint(b) + 0x8000u;
    return __builtin_amdgcn_perm(ub, ua, 0x07060302u);
}
__device__ __forceinline__ float bf_lo(unsigned u) { return __uint_as_float(u << 16); }
__device__ __forceinline__ float bf_hi(unsigned u) { return __uint_as_float(u & 0xFFFF0000u); }

// ---------------------------------------------------------------------------
// Merged prep + hist.
// ---------------------------------------------------------------------------
__global__ __launch_bounds__(256) void prep_hist_k(
    const float* __restrict__ Wsrc, const float* __restrict__ Wtgt,
    const float* __restrict__ Wskip, const float* __restrict__ W1,
    const float* __restrict__ W2, const float* __restrict__ b2,
    const float* __restrict__ Wg,
    unsigned short* __restrict__ Wall, float* __restrict__ w2g,
    const int* __restrict__ eidx, int E, int* __restrict__ deg)
{
    const int nhist = (E + 255) / 256;
    if ((int)blockIdx.x < nhist) {
        const int e = blockIdx.x * 256 + threadIdx.x;
        if (e < E) atomicAdd(deg + eidx[(size_t)E + e], 1);
        return;
    }
    const int b = blockIdx.x - nhist;
    if (b == (5 * DIM * DIM) / 256) {   // w2g block
        const int k = threadIdx.x;
        if (k < DIM) {
            float s = 0.f;
            for (int d = 0; d < DIM; ++d) s += W2[k * DIM + d] * Wg[d];
            w2g[k] = s;
        } else if (k == DIM) {
            float s = 0.f;
            for (int d = 0; d < DIM; ++d) s += b2[d] * Wg[d];
            w2g[DIM] = s;
        }
        return;
    }
    const int idx = b * 256 + threadIdx.x;
    const int m = idx >> 14;
    const int r = idx & 16383;
    const int n = r >> 7, k = r & 127;
    const float* W = (m == 0) ? Wsrc : (m == 1) ? Wtgt : (m == 2) ? Wskip : (m == 3) ? W1 : W2;
    Wall[idx] = f2bf(W[k * DIM + n]);
}

// ---------------------------------------------------------------------------
// Single-block scan, LDS-staged.
// ---------------------------------------------------------------------------
__global__ __launch_bounds__(256) void scan_k(const int* __restrict__ deg,
                                              int* __restrict__ rowptr,
                                              int* __restrict__ cursor, int N)
{
    __shared__ int part[256];
    const int t = threadIdx.x;

    if (N <= NMAX) {
        __shared__ int s[NMAX];
        for (int k = t; k < N; k += 256) s[k] = deg[k];
        __syncthreads();

        const int chunk = (N + 255) / 256;
        const int lo = min(t * chunk, N), hi = min(lo + chunk, N);
        int sum = 0;
        for (int k = lo; k < hi; ++k) sum += s[k];
        part[t] = sum;
        __syncthreads();
        for (int off = 1; off < 256; off <<= 1) {
            int u = (t >= off) ? part[t - off] : 0;
            __syncthreads();
            part[t] += u;
            __syncthreads();
        }
        int run = part[t] - sum;
        for (int k = lo; k < hi; ++k) { const int d = s[k]; s[k] = run; run += d; }
        __syncthreads();
        for (int k = t; k < N; k += 256) {
            const int v = s[k];
            rowptr[k] = v;
            cursor[k] = v;
        }
        if (t == 0) rowptr[N] = part[255];
    } else {
        const int chunk = (N + 255) / 256;
        const int lo = min(t * chunk, N), hi = min(lo + chunk, N);
        int s = 0;
        for (int k = lo; k < hi; ++k) s += deg[k];
        part[t] = s;
        __syncthreads();
        for (int off = 1; off < 256; off <<= 1) {
            int u = (t >= off) ? part[t - off] : 0;
            __syncthreads();
            part[t] += u;
            __syncthreads();
        }
        int run = part[t] - s;
        for (int k = lo; k < hi; ++k) {
            rowptr[k] = run;
            cursor[k] = run;
            run += deg[k];
        }
        if (t == 255) rowptr[N] = part[255];
    }
}

// ---------------------------------------------------------------------------
// Merged scatter + node_linear.
// ---------------------------------------------------------------------------
__global__ __launch_bounds__(256) void scatter_node_k(
    const int* __restrict__ eidx, int E, int* __restrict__ cursor,
    int2* __restrict__ jip, int nscatter,
    const float* __restrict__ x,
    const unsigned short* __restrict__ Wall,
    const float* __restrict__ bsrc,
    unsigned short* __restrict__ msg_src, unsigned short* __restrict__ msg_tgt,
    float* __restrict__ skip, int N)
{
    if ((int)blockIdx.x < nscatter) {
        const int e = blockIdx.x * 256 + threadIdx.x;
        if (e < E) {
            const int j = eidx[e];
            const int i = eidx[(size_t)E + e];
            const int p = atomicAdd(cursor + i, 1);
            jip[p] = make_int2(j, i);
        }
        return;
    }

    __shared__ unsigned short xt[32 * HSTR];
    const int t = threadIdx.x;
    const int n0blk = (blockIdx.x - nscatter) * 32;
    const int w = t >> 6, lane = t & 63, col = lane & 15, quad = lane >> 4;

    for (int k = t; k < 32 * 16; k += 256) {
        const int row = k >> 4, o = k & 15;
        uint4 v = make_uint4(0, 0, 0, 0);
        if (n0blk + row < N) {
            const float4 a = *(const float4*)(x + (size_t)(n0blk + row) * DIM + o * 8);
            const float4 b = *(const float4*)(x + (size_t)(n0blk + row) * DIM + o * 8 + 4);
            v.x = pkbf(a.x, a.y); v.y = pkbf(a.z, a.w);
            v.z = pkbf(b.x, b.y); v.w = pkbf(b.z, b.w);
        }
        *(uint4*)(xt + row * HSTR + o * 8) = v;
    }
    __syncthreads();

    bfrag af[2][4];
    #pragma unroll
    for (int mt = 0; mt < 2; ++mt)
        #pragma unroll
        for (int ks = 0; ks < 4; ++ks)
            af[mt][ks] = *(const bfrag*)(xt + (mt * 16 + col) * HSTR + ks * 32 + quad * 8);

    for (int m = 0; m < 3; ++m) {
        const unsigned short* Wt = Wall + m * DIM * DIM;
        bfrag bw[2][4];
        #pragma unroll
        for (int nt = 0; nt < 2; ++nt)
            #pragma unroll
            for (int ks = 0; ks < 4; ++ks)
                bw[nt][ks] = *(const bfrag*)(Wt + (w * 32 + nt * 16 + col) * DIM + ks * 32 + quad * 8);

        f32x4 acc[2][2];
        #pragma unroll
        for (int mt = 0; mt < 2; ++mt)
            #pragma unroll
            for (int nt = 0; nt < 2; ++nt)
                acc[mt][nt] = f32x4{0.f, 0.f, 0.f, 0.f};

        #pragma unroll
        for (int mt = 0; mt < 2; ++mt)
            #pragma unroll
            for (int nt = 0; nt < 2; ++nt)
                #pragma unroll
                for (int ks = 0; ks < 4; ++ks)
                    acc[mt][nt] = __builtin_amdgcn_mfma_f32_16x16x32_bf16(
                        bw[nt][ks], af[mt][ks], acc[mt][nt], 0, 0, 0);

        #pragma unroll
        for (int mt = 0; mt < 2; ++mt) {
            const int node = n0blk + mt * 16 + col;
            if (node >= N) continue;
            #pragma unroll
            for (int nt = 0; nt < 2; ++nt) {
                const int f0 = w * 32 + nt * 16 + quad * 4;
                if (m == 2) {
                    float4 o;
                    o.x = acc[mt][nt][0]; o.y = acc[mt][nt][1];
                    o.z = acc[mt][nt][2]; o.w = acc[mt][nt][3];
                    *(float4*)(skip + (size_t)node * DIM + f0) = o;
                } else {
                    float b0 = 0.f, b1v = 0.f, b2v = 0.f, b3v = 0.f;
                    if (m == 0) {
                        const float4 bb = *(const float4*)(bsrc + f0);
                        b0 = bb.x; b1v = bb.y; b2v = bb.z; b3v = bb.w;
                    }
                    uint2 o;
                    o.x = pkbf(acc[mt][nt][0] + b0, acc[mt][nt][1] + b1v);
                    o.y = pkbf(acc[mt][nt][2] + b2v, acc[mt][nt][3] + b3v);
                    unsigned short* dst = (m == 0) ? msg_src : msg_tgt;
                    *(uint2*)(dst + (size_t)node * DIM + f0) = o;
                }
            }
        }
    }
}

// ---------------------------------------------------------------------------
// K2: persistent, software-pipelined per-edge GEMM1 + gate (R9-proven, 77 µs).
// ---------------------------------------------------------------------------
__global__ __launch_bounds__(256, 3) void edge_mlp_mfma(
    const int2* __restrict__ jip, int ntiles,
    const unsigned short* __restrict__ msg_src, const unsigned short* __restrict__ msg_tgt,
    const float* __restrict__ a0p,
    const unsigned short* __restrict__ W1t, const float* __restrict__ b1,
    const float* __restrict__ a1p,
    const float* __restrict__ w2g,
    unsigned short* __restrict__ h2buf,
    float* __restrict__ gate)
{
    __shared__ unsigned short h1[2][64 * HSTR];
    __shared__ float gate_part[2][4][64];

    const int t = threadIdx.x;
    const float a0 = *a0p, a1 = *a1p;
    const int w = t >> 6, lane = t & 63, col = lane & 15, quad = lane >> 4;
    const int o = t & 15, r0 = t >> 4;

    bfrag bw1[2][4];
    float4 b1q[2], wgq[2];
    #pragma unroll
    for (int nt = 0; nt < 2; ++nt) {
        const int n = w * 32 + nt * 16 + col;
        #pragma unroll
        for (int ks = 0; ks < 4; ++ks)
            bw1[nt][ks] = *(const bfrag*)(W1t + n * DIM + ks * 32 + quad * 8);
        const int nq = w * 32 + nt * 16 + quad * 4;
        b1q[nt] = *(const float4*)(b1 + nq);
        wgq[nt] = *(const float4*)(w2g + nq);
    }
    const float c2 = w2g[DIM];
    const int stride = gridDim.x;

    int tile = blockIdx.x;
    if (tile >= ntiles) return;

    int2 eA[4], eB[4];
    uint4 svA[4], svB[4];

    {
        const int p0 = tile * 64;
        #pragma unroll
        for (int i = 0; i < 4; ++i) eA[i] = jip[p0 + r0 + 16 * i];
        #pragma unroll
        for (int i = 0; i < 4; ++i)
            svA[i] = *(const uint4*)(msg_src + (size_t)eA[i].x * DIM + o * 8);
        const int tn = tile + stride;
        const int p1 = (tn < ntiles ? tn : tile) * 64;
        #pragma unroll
        for (int i = 0; i < 4; ++i) eB[i] = jip[p1 + r0 + 16 * i];
    }

    int buf = 0;
    int prev_p0 = -1;

    for (; tile < ntiles; tile += stride) {
        const int p0 = tile * 64;

        // 1. issue NEXT tile's random src loads
        #pragma unroll
        for (int i = 0; i < 4; ++i)
            svB[i] = *(const uint4*)(msg_src + (size_t)eB[i].x * DIM + o * 8);

        // 2. processing: tgt loads (L2-hot) + combine + LDS write
        #pragma unroll
        for (int i = 0; i < 4; ++i) {
            const uint4 gv = *(const uint4*)(msg_tgt + (size_t)eA[i].y * DIM + o * 8);
            uint4 hv;
            hv.x = pkbf(prelu_f(bf_lo(svA[i].x) + bf_lo(gv.x), a0),
                        prelu_f(bf_hi(svA[i].x) + bf_hi(gv.x), a0));
            hv.y = pkbf(prelu_f(bf_lo(svA[i].y) + bf_lo(gv.y), a0),
                        prelu_f(bf_hi(svA[i].y) + bf_hi(gv.y), a0));
            hv.z = pkbf(prelu_f(bf_lo(svA[i].z) + bf_lo(gv.z), a0),
                        prelu_f(bf_hi(svA[i].z) + bf_hi(gv.z), a0));
            hv.w = pkbf(prelu_f(bf_lo(svA[i].w) + bf_lo(gv.w), a0),
                        prelu_f(bf_hi(svA[i].w) + bf_hi(gv.w), a0));
            *(uint4*)(h1[buf] + (r0 + 16 * i) * HSTR + o * 8) = hv;
        }

        // 3. rotate idx; prefetch idx for tile+2*stride
        #pragma unroll
        for (int i = 0; i < 4; ++i) eA[i] = eB[i];
        {
            const int tnn = tile + 2 * stride;
            const int p2 = (tnn < ntiles ? tnn : tile) * 64;
            #pragma unroll
            for (int i = 0; i < 4; ++i) eB[i] = jip[p2 + r0 + 16 * i];
        }

        __syncthreads();

        // 3b. deferred gate write for PREVIOUS tile
        if (prev_p0 >= 0 && t < 64)
            gate[prev_p0 + t] = gate_part[1 - buf][0][t] + gate_part[1 - buf][1][t]
                              + gate_part[1 - buf][2][t] + gate_part[1 - buf][3][t] + c2;

        // 4. GEMM1 (transposed)
        f32x4 acc[4][2];
        #pragma unroll
        for (int mt = 0; mt < 4; ++mt)
            #pragma unroll
            for (int nt = 0; nt < 2; ++nt)
                acc[mt][nt] = f32x4{0.f, 0.f, 0.f, 0.f};

        #pragma unroll
        for (int mt = 0; mt < 4; ++mt) {
            bfrag af[4];
            #pragma unroll
            for (int ks = 0; ks < 4; ++ks)
                af[ks] = *(const bfrag*)(h1[buf] + (mt * 16 + col) * HSTR + ks * 32 + quad * 8);
            #pragma unroll
            for (int nt = 0; nt < 2; ++nt)
                #pragma unroll
                for (int ks = 0; ks < 4; ++ks)
                    acc[mt][nt] = __builtin_amdgcn_mfma_f32_16x16x32_bf16(
                        bw1[nt][ks], af[ks], acc[mt][nt], 0, 0, 0);
        }

        // 5. epilogue: prelu -> h2buf, gate partials
        #pragma unroll
        for (int mt = 0; mt < 4; ++mt) {
            const int m = mt * 16 + col;
            float g = 0.f;
            #pragma unroll
            for (int nt = 0; nt < 2; ++nt) {
                const int n0 = w * 32 + nt * 16 + quad * 4;
                const float p0v = prelu_f(acc[mt][nt][0] + b1q[nt].x, a1);
                const float p1v = prelu_f(acc[mt][nt][1] + b1q[nt].y, a1);
                const float p2v = prelu_f(acc[mt][nt][2] + b1q[nt].z, a1);
                const float p3v = prelu_f(acc[mt][nt][3] + b1q[nt].w, a1);
                uint2 ov;
                ov.x = pkbf(p0v, p1v);
                ov.y = pkbf(p2v, p3v);
                *(uint2*)(h2buf + (size_t)(p0 + m) * DIM + n0) = ov;
                g += p0v * wgq[nt].x + p1v * wgq[nt].y + p2v * wgq[nt].z + p3v * wgq[nt].w;
            }
            g += __shfl_xor(g, 16);
            g += __shfl_xor(g, 32);
            if (quad == 0) gate_part[buf][w][m] = g;
        }

        #pragma unroll
        for (int i = 0; i < 4; ++i) svA[i] = svB[i];
        prev_p0 = p0;
        buf ^= 1;
    }

    __syncthreads();
    if (t < 64)
        gate[prev_p0 + t] = gate_part[1 - buf][0][t] + gate_part[1 - buf][1][t]
                          + gate_part[1 - buf][2][t] + gate_part[1 - buf][3][t] + c2;
}

// ---------------------------------------------------------------------------
// K3: single-pass shift-free softmax aggregation. Wave per node (4/block,
// 5000 blocks): weight = exp(min(g,60)); normalization cancels shift exactly.
// Writes pre-normalized bf16 aggh2.
// ---------------------------------------------------------------------------
__global__ __launch_bounds__(256) void aggregate_h2_k(
    const int* __restrict__ rowptr,
    const float* __restrict__ gate, const unsigned short* __restrict__ h2buf,
    unsigned short* __restrict__ aggh2, int N)
{
    const int n = blockIdx.x * 4 + (threadIdx.x >> 6);
    const int lane = threadIdx.x & 63;
    if (n >= N) return;

    const int base = rowptr[n];
    const int deg = rowptr[n + 1] - base;
    const int grp = lane >> 4, sub = lane & 15;

    float acc[8] = {0.f, 0.f, 0.f, 0.f, 0.f, 0.f, 0.f, 0.f};
    float se = 0.f;
    for (int k = grp; k < deg; k += 4) {
        const float e = __expf(fminf(gate[base + k], 60.f));
        se += e;
        const uint4 mv = *(const uint4*)(h2buf + (size_t)(base + k) * DIM + sub * 8);
        acc[0] += e * bf_lo(mv.x); acc[1] += e * bf_hi(mv.x);
        acc[2] += e * bf_lo(mv.y); acc[3] += e * bf_hi(mv.y);
        acc[4] += e * bf_lo(mv.z); acc[5] += e * bf_hi(mv.z);
        acc[6] += e * bf_lo(mv.w); acc[7] += e * bf_hi(mv.w);
    }
    #pragma unroll
    for (int j = 0; j < 8; ++j) {
        acc[j] += __shfl_xor(acc[j], 16);
        acc[j] += __shfl_xor(acc[j], 32);
    }
    se += __shfl_xor(se, 16);
    se += __shfl_xor(se, 32);
    const float inv = 1.f / (se + 1e-16f);

    if (grp == 0) {
        uint4 ov;
        ov.x = pkbf(acc[0] * inv, acc[1] * inv);
        ov.y = pkbf(acc[2] * inv, acc[3] * inv);
        ov.z = pkbf(acc[4] * inv, acc[5] * inv);
        ov.w = pkbf(acc[6] * inv, acc[7] * inv);
        *(uint4*)(aggh2 + (size_t)n * DIM + sub * 8) = ov;
    }
}

// ---------------------------------------------------------------------------
// K4: out = LN(aggh2 @ W2 + b2 + skip) * gamma + beta, via bf16 MFMA.
// ---------------------------------------------------------------------------
__global__ __launch_bounds__(256) void node_out_k(
    const unsigned short* __restrict__ aggh2,
    const unsigned short* __restrict__ W2t, const float* __restrict__ b2,
    const float* __restrict__ skip,
    const float* __restrict__ gamma, const float* __restrict__ beta,
    float* __restrict__ out, int N)
{
    __shared__ unsigned short hh[64 * HSTR];
    __shared__ float ls1[4][4][16], ls2[4][4][16];

    const int t = threadIdx.x;
    const int n0blk = blockIdx.x * 64;
    const int w = t >> 6, lane = t & 63, col = lane & 15, quad = lane >> 4;

    bfrag bw2[2][4];
    float4 b2q[2];
    #pragma unroll
    for (int nt = 0; nt < 2; ++nt) {
        const int n = w * 32 + nt * 16 + col;
        #pragma unroll
        for (int ks = 0; ks < 4; ++ks)
            bw2[nt][ks] = *(const bfrag*)(W2t + n * DIM + ks * 32 + quad * 8);
        b2q[nt] = *(const float4*)(b2 + w * 32 + nt * 16 + quad * 4);
    }

    for (int k = t; k < 64 * 16; k += 256) {
        const int row = k >> 4, o = k & 15;
        uint4 v = make_uint4(0, 0, 0, 0);
        if (n0blk + row < N) v = *(const uint4*)(aggh2 + (size_t)(n0blk + row) * DIM + o * 8);
        *(uint4*)(hh + row * HSTR + o * 8) = v;
    }
    __syncthreads();

    f32x4 acc[4][2];
    #pragma unroll
    for (int mt = 0; mt < 4; ++mt)
        #pragma unroll
        for (int nt = 0; nt < 2; ++nt)
            acc[mt][nt] = f32x4{0.f, 0.f, 0.f, 0.f};

    #pragma unroll
    for (int mt = 0; mt < 4; ++mt) {
        bfrag af[4];
        #pragma unroll
        for (int ks = 0; ks < 4; ++ks)
            af[ks] = *(const bfrag*)(hh + (mt * 16 + col) * HSTR + ks * 32 + quad * 8);
        #pragma unroll
        for (int nt = 0; nt < 2; ++nt)
            #pragma unroll
            for (int ks = 0; ks < 4; ++ks)
                acc[mt][nt] = __builtin_amdgcn_mfma_f32_16x16x32_bf16(
                    bw2[nt][ks], af[ks], acc[mt][nt], 0, 0, 0);
    }

    float v[4][2][4];
    #pragma unroll
    for (int mt = 0; mt < 4; ++mt) {
        const int node = n0blk + mt * 16 + col;
        float s1 = 0.f, s2 = 0.f;
        #pragma unroll
        for (int nt = 0; nt < 2; ++nt) {
            const int f0 = w * 32 + nt * 16 + quad * 4;
            float4 sk = make_float4(0.f, 0.f, 0.f, 0.f);
            if (node < N) sk = *(const float4*)(skip + (size_t)node * DIM + f0);
            v[mt][nt][0] = acc[mt][nt][0] + b2q[nt].x + sk.x;
            v[mt][nt][1] = acc[mt][nt][1] + b2q[nt].y + sk.y;
            v[mt][nt][2] = acc[mt][nt][2] + b2q[nt].z + sk.z;
            v[mt][nt][3] = acc[mt][nt][3] + b2q[nt].w + sk.w;
            #pragma unroll
            for (int r = 0; r < 4; ++r) {
                s1 += v[mt][nt][r];
                s2 += v[mt][nt][r] * v[mt][nt][r];
            }
        }
        s1 += __shfl_xor(s1, 16); s1 += __shfl_xor(s1, 32);
        s2 += __shfl_xor(s2, 16); s2 += __shfl_xor(s2, 32);
        if (quad == 0) { ls1[w][mt][col] = s1; ls2[w][mt][col] = s2; }
    }
    __syncthreads();

    #pragma unroll
    for (int mt = 0; mt < 4; ++mt) {
        const int node = n0blk + mt * 16 + col;
        if (node >= N) continue;
        const float sum = ls1[0][mt][col] + ls1[1][mt][col] + ls1[2][mt][col] + ls1[3][mt][col];
        const float sq  = ls2[0][mt][col] + ls2[1][mt][col] + ls2[2][mt][col] + ls2[3][mt][col];
        const float mu = sum * (1.f / 128.f);
        const float var = sq * (1.f / 128.f) - mu * mu;
        const float rs = rsqrtf(var + 1e-5f);
        #pragma unroll
        for (int nt = 0; nt < 2; ++nt) {
            const int f0 = w * 32 + nt * 16 + quad * 4;
            const float4 gm = *(const float4*)(gamma + f0);
            const float4 bt = *(const float4*)(beta + f0);
            float4 ov;
            ov.x = (v[mt][nt][0] - mu) * rs * gm.x + bt.x;
            ov.y = (v[mt][nt][1] - mu) * rs * gm.y + bt.y;
            ov.z = (v[mt][nt][2] - mu) * rs * gm.z + bt.z;
            ov.w = (v[mt][nt][3] - mu) * rs * gm.w + bt.w;
            *(float4*)(out + (size_t)node * DIM + f0) = ov;
        }
    }
}

// ---------------------------------------------------------------------------
extern "C" void kernel_launch(void* const* d_in, const int* in_sizes, int n_in,
                              void* d_out, int out_size, void* d_ws, size_t ws_size,
                              hipStream_t stream)
{
    const float* x     = (const float*)d_in[0];
    const int*   eidx  = (const int*)d_in[1];
    const float* Wsrc  = (const float*)d_in[2];
    const float* bsrc  = (const float*)d_in[3];
    const float* Wtgt  = (const float*)d_in[4];
    const float* Wskip = (const float*)d_in[5];
    const float* a0    = (const float*)d_in[6];
    const float* W1    = (const float*)d_in[7];
    const float* b1    = (const float*)d_in[8];
    const float* a1    = (const float*)d_in[9];
    const float* W2    = (const float*)d_in[10];
    const float* b2    = (const float*)d_in[11];
    const float* Wg    = (const float*)d_in[12];
    const float* gamma = (const float*)d_in[13];
    const float* beta  = (const float*)d_in[14];

    const int N = in_sizes[0] / DIM;      // 20000
    const int E = in_sizes[1] / 2;        // 640000
    const int Npad = ((N + 63) / 64) * 64;
    float* out = (float*)d_out;

    char* ws = (char*)d_ws;
    size_t off = 0;
    auto alloc = [&](size_t bytes) -> void* {
        void* p = ws + off;
        off += (bytes + 255) & ~(size_t)255;
        return p;
    };
    unsigned short* msg_src = (unsigned short*)alloc((size_t)N * DIM * 2);
    unsigned short* msg_tgt = (unsigned short*)alloc((size_t)N * DIM * 2);
    float*          skip    = (float*)alloc((size_t)N * DIM * 4);
    float*          gate    = (float*)alloc((size_t)E * 4);
    int*            deg     = (int*)alloc((size_t)N * 4);
    int*            rowptr  = (int*)alloc((size_t)(N + 1) * 4);
    int*            cursor  = (int*)alloc((size_t)N * 4);
    int2*           jip     = (int2*)alloc((size_t)E * 8);
    unsigned short* Wall    = (unsigned short*)alloc((size_t)5 * DIM * DIM * 2);
    float*          w2g     = (float*)alloc((size_t)(DIM + 1) * 4);
    unsigned short* aggh2   = (unsigned short*)alloc((size_t)Npad * DIM * 2);
    unsigned short* h2buf   = (unsigned short*)alloc((size_t)E * DIM * 2);
    (void)ws_size; (void)n_in; (void)out_size;

    hipMemsetAsync(deg, 0, (size_t)N * 4, stream);
    if (Npad > N)
        hipMemsetAsync(aggh2 + (size_t)N * DIM, 0, (size_t)(Npad - N) * DIM * 2, stream);

    const int nhist = (E + 255) / 256;
    prep_hist_k<<<nhist + (5 * DIM * DIM) / 256 + 1, 256, 0, stream>>>(
        Wsrc, Wtgt, Wskip, W1, W2, b2, Wg, Wall, w2g, eidx, E, deg);

    scan_k<<<1, 256, 0, stream>>>(deg, rowptr, cursor, N);

    const int nscatter = (E + 255) / 256;
    const int nnode = (N + 31) / 32;
    scatter_node_k<<<nscatter + nnode, 256, 0, stream>>>(
        eidx, E, cursor, jip, nscatter,
        x, Wall, bsrc, msg_src, msg_tgt, skip, N);

    const int ntiles = E / 64;
    const int egrid = ntiles < 1024 ? ntiles : 1024;
    edge_mlp_mfma<<<egrid, 256, 0, stream>>>(jip, ntiles, msg_src, msg_tgt, a0,
                                             Wall + 3 * DIM * DIM, b1, a1,
                                             w2g, h2buf, gate);

    aggregate_h2_k<<<(N + 3) / 4, 256, 0, stream>>>(rowptr, gate, h2buf, aggh2, N);

    node_out_k<<<Npad / 64, 256, 0, stream>>>(aggh2, Wall + 4 * DIM * DIM, b2, skip,
                                              gamma, beta, out, N);
}

// Round 13
// 291.240 us; speedup vs baseline: 1.4603x; 1.0103x over previous
//
#include <hip/hip_runtime.h>
#include <hip/hip_bf16.h>
#include <stdint.h>

// Problem constants (reference: N=20000, E=640000, C=D=M=128)
#define DIM 128
#define HSTR 136    // padded LDS row stride in bf16 elems (272 B, 16B-aligned rows)
#define NMAX 20224  // LDS-staged scan capacity

using bfrag = __attribute__((ext_vector_type(8))) short;   // 8 bf16 (4 VGPRs)
using f32x4 = __attribute__((ext_vector_type(4))) float;   // MFMA C/D
using f32x2 = __attribute__((ext_vector_type(2))) float;

__device__ __forceinline__ float prelu_f(float v, float a) { return v >= 0.f ? v : a * v; }

// RNE bf16 (cold prep paths)
__device__ __forceinline__ unsigned short f2bf(float f) {
    unsigned u = __float_as_uint(f);
    unsigned r = (u + 0x7FFFu + ((u >> 16) & 1u)) >> 16;
    return (unsigned short)r;
}
// Hot path: round-half-up bf16, pack two -> u32 (a->lo16, b->hi16).
__device__ __forceinline__ unsigned pkbf(float a, float b) {
    const unsigned ua = __float_as_uint(a) + 0x8000u;
    const unsigned ub = __float_as_uint(b) + 0x8000u;
    return __builtin_amdgcn_perm(ub, ua, 0x07060302u);
}
__device__ __forceinline__ float bf_lo(unsigned u) { return __uint_as_float(u << 16); }
__device__ __forceinline__ float bf_hi(unsigned u) { return __uint_as_float(u & 0xFFFF0000u); }

// ---------------------------------------------------------------------------
// Merged prep + hist.
// ---------------------------------------------------------------------------
__global__ __launch_bounds__(256) void prep_hist_k(
    const float* __restrict__ Wsrc, const float* __restrict__ Wtgt,
    const float* __restrict__ Wskip, const float* __restrict__ W1,
    const float* __restrict__ W2, const float* __restrict__ b2,
    const float* __restrict__ Wg,
    unsigned short* __restrict__ Wall, float* __restrict__ w2g,
    const int* __restrict__ eidx, int E, int* __restrict__ deg)
{
    const int nhist = (E + 255) / 256;
    if ((int)blockIdx.x < nhist) {
        const int e = blockIdx.x * 256 + threadIdx.x;
        if (e < E) atomicAdd(deg + eidx[(size_t)E + e], 1);
        return;
    }
    const int b = blockIdx.x - nhist;
    if (b == (5 * DIM * DIM) / 256) {   // w2g block
        const int k = threadIdx.x;
        if (k < DIM) {
            float s = 0.f;
            for (int d = 0; d < DIM; ++d) s += W2[k * DIM + d] * Wg[d];
            w2g[k] = s;
        } else if (k == DIM) {
            float s = 0.f;
            for (int d = 0; d < DIM; ++d) s += b2[d] * Wg[d];
            w2g[DIM] = s;
        }
        return;
    }
    const int idx = b * 256 + threadIdx.x;
    const int m = idx >> 14;
    const int r = idx & 16383;
    const int n = r >> 7, k = r & 127;
    const float* W = (m == 0) ? Wsrc : (m == 1) ? Wtgt : (m == 2) ? Wskip : (m == 3) ? W1 : W2;
    Wall[idx] = f2bf(W[k * DIM + n]);
}

// ---------------------------------------------------------------------------
// Single-block scan, LDS-staged.
// ---------------------------------------------------------------------------
__global__ __launch_bounds__(256) void scan_k(const int* __restrict__ deg,
                                              int* __restrict__ rowptr,
                                              int* __restrict__ cursor, int N)
{
    __shared__ int part[256];
    const int t = threadIdx.x;

    if (N <= NMAX) {
        __shared__ int s[NMAX];
        for (int k = t; k < N; k += 256) s[k] = deg[k];
        __syncthreads();

        const int chunk = (N + 255) / 256;
        const int lo = min(t * chunk, N), hi = min(lo + chunk, N);
        int sum = 0;
        for (int k = lo; k < hi; ++k) sum += s[k];
        part[t] = sum;
        __syncthreads();
        for (int off = 1; off < 256; off <<= 1) {
            int u = (t >= off) ? part[t - off] : 0;
            __syncthreads();
            part[t] += u;
            __syncthreads();
        }
        int run = part[t] - sum;
        for (int k = lo; k < hi; ++k) { const int d = s[k]; s[k] = run; run += d; }
        __syncthreads();
        for (int k = t; k < N; k += 256) {
            const int v = s[k];
            rowptr[k] = v;
            cursor[k] = v;
        }
        if (t == 0) rowptr[N] = part[255];
    } else {
        const int chunk = (N + 255) / 256;
        const int lo = min(t * chunk, N), hi = min(lo + chunk, N);
        int s = 0;
        for (int k = lo; k < hi; ++k) s += deg[k];
        part[t] = s;
        __syncthreads();
        for (int off = 1; off < 256; off <<= 1) {
            int u = (t >= off) ? part[t - off] : 0;
            __syncthreads();
            part[t] += u;
            __syncthreads();
        }
        int run = part[t] - s;
        for (int k = lo; k < hi; ++k) {
            rowptr[k] = run;
            cursor[k] = run;
            run += deg[k];
        }
        if (t == 255) rowptr[N] = part[255];
    }
}

// ---------------------------------------------------------------------------
// Merged scatter + node_linear.
// ---------------------------------------------------------------------------
__global__ __launch_bounds__(256) void scatter_node_k(
    const int* __restrict__ eidx, int E, int* __restrict__ cursor,
    int2* __restrict__ jip, int nscatter,
    const float* __restrict__ x,
    const unsigned short* __restrict__ Wall,
    const float* __restrict__ bsrc,
    unsigned short* __restrict__ msg_src, unsigned short* __restrict__ msg_tgt,
    float* __restrict__ skip, int N)
{
    if ((int)blockIdx.x < nscatter) {
        const int e = blockIdx.x * 256 + threadIdx.x;
        if (e < E) {
            const int j = eidx[e];
            const int i = eidx[(size_t)E + e];
            const int p = atomicAdd(cursor + i, 1);
            jip[p] = make_int2(j, i);
        }
        return;
    }

    __shared__ unsigned short xt[32 * HSTR];
    const int t = threadIdx.x;
    const int n0blk = (blockIdx.x - nscatter) * 32;
    const int w = t >> 6, lane = t & 63, col = lane & 15, quad = lane >> 4;

    for (int k = t; k < 32 * 16; k += 256) {
        const int row = k >> 4, o = k & 15;
        uint4 v = make_uint4(0, 0, 0, 0);
        if (n0blk + row < N) {
            const float4 a = *(const float4*)(x + (size_t)(n0blk + row) * DIM + o * 8);
            const float4 b = *(const float4*)(x + (size_t)(n0blk + row) * DIM + o * 8 + 4);
            v.x = pkbf(a.x, a.y); v.y = pkbf(a.z, a.w);
            v.z = pkbf(b.x, b.y); v.w = pkbf(b.z, b.w);
        }
        *(uint4*)(xt + row * HSTR + o * 8) = v;
    }
    __syncthreads();

    bfrag af[2][4];
    #pragma unroll
    for (int mt = 0; mt < 2; ++mt)
        #pragma unroll
        for (int ks = 0; ks < 4; ++ks)
            af[mt][ks] = *(const bfrag*)(xt + (mt * 16 + col) * HSTR + ks * 32 + quad * 8);

    for (int m = 0; m < 3; ++m) {
        const unsigned short* Wt = Wall + m * DIM * DIM;
        bfrag bw[2][4];
        #pragma unroll
        for (int nt = 0; nt < 2; ++nt)
            #pragma unroll
            for (int ks = 0; ks < 4; ++ks)
                bw[nt][ks] = *(const bfrag*)(Wt + (w * 32 + nt * 16 + col) * DIM + ks * 32 + quad * 8);

        f32x4 acc[2][2];
        #pragma unroll
        for (int mt = 0; mt < 2; ++mt)
            #pragma unroll
            for (int nt = 0; nt < 2; ++nt)
                acc[mt][nt] = f32x4{0.f, 0.f, 0.f, 0.f};

        #pragma unroll
        for (int mt = 0; mt < 2; ++mt)
            #pragma unroll
            for (int nt = 0; nt < 2; ++nt)
                #pragma unroll
                for (int ks = 0; ks < 4; ++ks)
                    acc[mt][nt] = __builtin_amdgcn_mfma_f32_16x16x32_bf16(
                        bw[nt][ks], af[mt][ks], acc[mt][nt], 0, 0, 0);

        #pragma unroll
        for (int mt = 0; mt < 2; ++mt) {
            const int node = n0blk + mt * 16 + col;
            if (node >= N) continue;
            #pragma unroll
            for (int nt = 0; nt < 2; ++nt) {
                const int f0 = w * 32 + nt * 16 + quad * 4;
                if (m == 2) {
                    float4 o;
                    o.x = acc[mt][nt][0]; o.y = acc[mt][nt][1];
                    o.z = acc[mt][nt][2]; o.w = acc[mt][nt][3];
                    *(float4*)(skip + (size_t)node * DIM + f0) = o;
                } else {
                    float b0 = 0.f, b1v = 0.f, b2v = 0.f, b3v = 0.f;
                    if (m == 0) {
                        const float4 bb = *(const float4*)(bsrc + f0);
                        b0 = bb.x; b1v = bb.y; b2v = bb.z; b3v = bb.w;
                    }
                    uint2 o;
                    o.x = pkbf(acc[mt][nt][0] + b0, acc[mt][nt][1] + b1v);
                    o.y = pkbf(acc[mt][nt][2] + b2v, acc[mt][nt][3] + b3v);
                    unsigned short* dst = (m == 0) ? msg_src : msg_tgt;
                    *(uint2*)(dst + (size_t)node * DIM + f0) = o;
                }
            }
        }
    }
}

// ---------------------------------------------------------------------------
// K2: persistent, software-pipelined per-edge GEMM1 + gate.
// h2buf stored as fp8 e4m3 (storage-only; gate/softmax math stays fp32).
// ---------------------------------------------------------------------------
__global__ __launch_bounds__(256, 3) void edge_mlp_mfma(
    const int2* __restrict__ jip, int ntiles,
    const unsigned short* __restrict__ msg_src, const unsigned short* __restrict__ msg_tgt,
    const float* __restrict__ a0p,
    const unsigned short* __restrict__ W1t, const float* __restrict__ b1,
    const float* __restrict__ a1p,
    const float* __restrict__ w2g,
    unsigned char* __restrict__ h2buf,      // fp8 e4m3 [E,128], perm order
    float* __restrict__ gate)
{
    __shared__ unsigned short h1[2][64 * HSTR];
    __shared__ float gate_part[2][4][64];

    const int t = threadIdx.x;
    const float a0 = *a0p, a1 = *a1p;
    const int w = t >> 6, lane = t & 63, col = lane & 15, quad = lane >> 4;
    const int o = t & 15, r0 = t >> 4;

    bfrag bw1[2][4];
    float4 b1q[2], wgq[2];
    #pragma unroll
    for (int nt = 0; nt < 2; ++nt) {
        const int n = w * 32 + nt * 16 + col;
        #pragma unroll
        for (int ks = 0; ks < 4; ++ks)
            bw1[nt][ks] = *(const bfrag*)(W1t + n * DIM + ks * 32 + quad * 8);
        const int nq = w * 32 + nt * 16 + quad * 4;
        b1q[nt] = *(const float4*)(b1 + nq);
        wgq[nt] = *(const float4*)(w2g + nq);
    }
    const float c2 = w2g[DIM];
    const int stride = gridDim.x;

    int tile = blockIdx.x;
    if (tile >= ntiles) return;

    int2 eA[4], eB[4];
    uint4 svA[4], svB[4];

    {
        const int p0 = tile * 64;
        #pragma unroll
        for (int i = 0; i < 4; ++i) eA[i] = jip[p0 + r0 + 16 * i];
        #pragma unroll
        for (int i = 0; i < 4; ++i)
            svA[i] = *(const uint4*)(msg_src + (size_t)eA[i].x * DIM + o * 8);
        const int tn = tile + stride;
        const int p1 = (tn < ntiles ? tn : tile) * 64;
        #pragma unroll
        for (int i = 0; i < 4; ++i) eB[i] = jip[p1 + r0 + 16 * i];
    }

    int buf = 0;
    int prev_p0 = -1;

    for (; tile < ntiles; tile += stride) {
        const int p0 = tile * 64;

        // 1. issue NEXT tile's random src loads
        #pragma unroll
        for (int i = 0; i < 4; ++i)
            svB[i] = *(const uint4*)(msg_src + (size_t)eB[i].x * DIM + o * 8);

        // 2. processing: tgt loads (L2-hot) + combine + LDS write
        #pragma unroll
        for (int i = 0; i < 4; ++i) {
            const uint4 gv = *(const uint4*)(msg_tgt + (size_t)eA[i].y * DIM + o * 8);
            uint4 hv;
            hv.x = pkbf(prelu_f(bf_lo(svA[i].x) + bf_lo(gv.x), a0),
                        prelu_f(bf_hi(svA[i].x) + bf_hi(gv.x), a0));
            hv.y = pkbf(prelu_f(bf_lo(svA[i].y) + bf_lo(gv.y), a0),
                        prelu_f(bf_hi(svA[i].y) + bf_hi(gv.y), a0));
            hv.z = pkbf(prelu_f(bf_lo(svA[i].z) + bf_lo(gv.z), a0),
                        prelu_f(bf_hi(svA[i].z) + bf_hi(gv.z), a0));
            hv.w = pkbf(prelu_f(bf_lo(svA[i].w) + bf_lo(gv.w), a0),
                        prelu_f(bf_hi(svA[i].w) + bf_hi(gv.w), a0));
            *(uint4*)(h1[buf] + (r0 + 16 * i) * HSTR + o * 8) = hv;
        }

        // 3. rotate idx; prefetch idx for tile+2*stride
        #pragma unroll
        for (int i = 0; i < 4; ++i) eA[i] = eB[i];
        {
            const int tnn = tile + 2 * stride;
            const int p2 = (tnn < ntiles ? tnn : tile) * 64;
            #pragma unroll
            for (int i = 0; i < 4; ++i) eB[i] = jip[p2 + r0 + 16 * i];
        }

        __syncthreads();

        // 3b. deferred gate write for PREVIOUS tile
        if (prev_p0 >= 0 && t < 64)
            gate[prev_p0 + t] = gate_part[1 - buf][0][t] + gate_part[1 - buf][1][t]
                              + gate_part[1 - buf][2][t] + gate_part[1 - buf][3][t] + c2;

        // 4. GEMM1 (transposed)
        f32x4 acc[4][2];
        #pragma unroll
        for (int mt = 0; mt < 4; ++mt)
            #pragma unroll
            for (int nt = 0; nt < 2; ++nt)
                acc[mt][nt] = f32x4{0.f, 0.f, 0.f, 0.f};

        #pragma unroll
        for (int mt = 0; mt < 4; ++mt) {
            bfrag af[4];
            #pragma unroll
            for (int ks = 0; ks < 4; ++ks)
                af[ks] = *(const bfrag*)(h1[buf] + (mt * 16 + col) * HSTR + ks * 32 + quad * 8);
            #pragma unroll
            for (int nt = 0; nt < 2; ++nt)
                #pragma unroll
                for (int ks = 0; ks < 4; ++ks)
                    acc[mt][nt] = __builtin_amdgcn_mfma_f32_16x16x32_bf16(
                        bw1[nt][ks], af[ks], acc[mt][nt], 0, 0, 0);
        }

        // 5. epilogue: prelu -> h2buf (fp8), gate partials (fp32)
        #pragma unroll
        for (int mt = 0; mt < 4; ++mt) {
            const int m = mt * 16 + col;
            float g = 0.f;
            #pragma unroll
            for (int nt = 0; nt < 2; ++nt) {
                const int n0 = w * 32 + nt * 16 + quad * 4;
                const float p0v = prelu_f(acc[mt][nt][0] + b1q[nt].x, a1);
                const float p1v = prelu_f(acc[mt][nt][1] + b1q[nt].y, a1);
                const float p2v = prelu_f(acc[mt][nt][2] + b1q[nt].z, a1);
                const float p3v = prelu_f(acc[mt][nt][3] + b1q[nt].w, a1);
                int pk = __builtin_amdgcn_cvt_pk_fp8_f32(p0v, p1v, 0, false);
                pk = __builtin_amdgcn_cvt_pk_fp8_f32(p2v, p3v, pk, true);
                *(unsigned*)(h2buf + (size_t)(p0 + m) * DIM + n0) = (unsigned)pk;
                g += p0v * wgq[nt].x + p1v * wgq[nt].y + p2v * wgq[nt].z + p3v * wgq[nt].w;
            }
            g += __shfl_xor(g, 16);
            g += __shfl_xor(g, 32);
            if (quad == 0) gate_part[buf][w][m] = g;
        }

        #pragma unroll
        for (int i = 0; i < 4; ++i) svA[i] = svB[i];
        prev_p0 = p0;
        buf ^= 1;
    }

    __syncthreads();
    if (t < 64)
        gate[prev_p0 + t] = gate_part[1 - buf][0][t] + gate_part[1 - buf][1][t]
                          + gate_part[1 - buf][2][t] + gate_part[1 - buf][3][t] + c2;
}

// ---------------------------------------------------------------------------
// K3: single-pass shift-free softmax aggregation over fp8 h2buf.
// Wave per node (4/block): weight = exp(min(g,60)); normalization cancels
// the shift exactly. Writes pre-normalized bf16 aggh2.
// ---------------------------------------------------------------------------
__global__ __launch_bounds__(256) void aggregate_h2_k(
    const int* __restrict__ rowptr,
    const float* __restrict__ gate, const unsigned char* __restrict__ h2buf,
    unsigned short* __restrict__ aggh2, int N)
{
    const int n = blockIdx.x * 4 + (threadIdx.x >> 6);
    const int lane = threadIdx.x & 63;
    if (n >= N) return;

    const int base = rowptr[n];
    const int deg = rowptr[n + 1] - base;
    const int grp = lane >> 4, sub = lane & 15;

    float acc[8] = {0.f, 0.f, 0.f, 0.f, 0.f, 0.f, 0.f, 0.f};
    float se = 0.f;
    for (int k = grp; k < deg; k += 4) {
        const float e = __expf(fminf(gate[base + k], 60.f));
        se += e;
        const uint2 mv = *(const uint2*)(h2buf + (size_t)(base + k) * DIM + sub * 8);
        const f32x2 f01 = __builtin_amdgcn_cvt_pk_f32_fp8(mv.x, false);
        const f32x2 f23 = __builtin_amdgcn_cvt_pk_f32_fp8(mv.x, true);
        const f32x2 f45 = __builtin_amdgcn_cvt_pk_f32_fp8(mv.y, false);
        const f32x2 f67 = __builtin_amdgcn_cvt_pk_f32_fp8(mv.y, true);
        acc[0] += e * f01.x; acc[1] += e * f01.y;
        acc[2] += e * f23.x; acc[3] += e * f23.y;
        acc[4] += e * f45.x; acc[5] += e * f45.y;
        acc[6] += e * f67.x; acc[7] += e * f67.y;
    }
    #pragma unroll
    for (int j = 0; j < 8; ++j) {
        acc[j] += __shfl_xor(acc[j], 16);
        acc[j] += __shfl_xor(acc[j], 32);
    }
    se += __shfl_xor(se, 16);
    se += __shfl_xor(se, 32);
    const float inv = 1.f / (se + 1e-16f);

    if (grp == 0) {
        uint4 ov;
        ov.x = pkbf(acc[0] * inv, acc[1] * inv);
        ov.y = pkbf(acc[2] * inv, acc[3] * inv);
        ov.z = pkbf(acc[4] * inv, acc[5] * inv);
        ov.w = pkbf(acc[6] * inv, acc[7] * inv);
        *(uint4*)(aggh2 + (size_t)n * DIM + sub * 8) = ov;
    }
}

// ---------------------------------------------------------------------------
// K4: out = LN(aggh2 @ W2 + b2 + skip) * gamma + beta, via bf16 MFMA.
// ---------------------------------------------------------------------------
__global__ __launch_bounds__(256) void node_out_k(
    const unsigned short* __restrict__ aggh2,
    const unsigned short* __restrict__ W2t, const float* __restrict__ b2,
    const float* __restrict__ skip,
    const float* __restrict__ gamma, const float* __restrict__ beta,
    float* __restrict__ out, int N)
{
    __shared__ unsigned short hh[64 * HSTR];
    __shared__ float ls1[4][4][16], ls2[4][4][16];

    const int t = threadIdx.x;
    const int n0blk = blockIdx.x * 64;
    const int w = t >> 6, lane = t & 63, col = lane & 15, quad = lane >> 4;

    bfrag bw2[2][4];
    float4 b2q[2];
    #pragma unroll
    for (int nt = 0; nt < 2; ++nt) {
        const int n = w * 32 + nt * 16 + col;
        #pragma unroll
        for (int ks = 0; ks < 4; ++ks)
            bw2[nt][ks] = *(const bfrag*)(W2t + n * DIM + ks * 32 + quad * 8);
        b2q[nt] = *(const float4*)(b2 + w * 32 + nt * 16 + quad * 4);
    }

    for (int k = t; k < 64 * 16; k += 256) {
        const int row = k >> 4, o = k & 15;
        uint4 v = make_uint4(0, 0, 0, 0);
        if (n0blk + row < N) v = *(const uint4*)(aggh2 + (size_t)(n0blk + row) * DIM + o * 8);
        *(uint4*)(hh + row * HSTR + o * 8) = v;
    }
    __syncthreads();

    f32x4 acc[4][2];
    #pragma unroll
    for (int mt = 0; mt < 4; ++mt)
        #pragma unroll
        for (int nt = 0; nt < 2; ++nt)
            acc[mt][nt] = f32x4{0.f, 0.f, 0.f, 0.f};

    #pragma unroll
    for (int mt = 0; mt < 4; ++mt) {
        bfrag af[4];
        #pragma unroll
        for (int ks = 0; ks < 4; ++ks)
            af[ks] = *(const bfrag*)(hh + (mt * 16 + col) * HSTR + ks * 32 + quad * 8);
        #pragma unroll
        for (int nt = 0; nt < 2; ++nt)
            #pragma unroll
            for (int ks = 0; ks < 4; ++ks)
                acc[mt][nt] = __builtin_amdgcn_mfma_f32_16x16x32_bf16(
                    bw2[nt][ks], af[ks], acc[mt][nt], 0, 0, 0);
    }

    float v[4][2][4];
    #pragma unroll
    for (int mt = 0; mt < 4; ++mt) {
        const int node = n0blk + mt * 16 + col;
        float s1 = 0.f, s2 = 0.f;
        #pragma unroll
        for (int nt = 0; nt < 2; ++nt) {
            const int f0 = w * 32 + nt * 16 + quad * 4;
            float4 sk = make_float4(0.f, 0.f, 0.f, 0.f);
            if (node < N) sk = *(const float4*)(skip + (size_t)node * DIM + f0);
            v[mt][nt][0] = acc[mt][nt][0] + b2q[nt].x + sk.x;
            v[mt][nt][1] = acc[mt][nt][1] + b2q[nt].y + sk.y;
            v[mt][nt][2] = acc[mt][nt][2] + b2q[nt].z + sk.z;
            v[mt][nt][3] = acc[mt][nt][3] + b2q[nt].w + sk.w;
            #pragma unroll
            for (int r = 0; r < 4; ++r) {
                s1 += v[mt][nt][r];
                s2 += v[mt][nt][r] * v[mt][nt][r];
            }
        }
        s1 += __shfl_xor(s1, 16); s1 += __shfl_xor(s1, 32);
        s2 += __shfl_xor(s2, 16); s2 += __shfl_xor(s2, 32);
        if (quad == 0) { ls1[w][mt][col] = s1; ls2[w][mt][col] = s2; }
    }
    __syncthreads();

    #pragma unroll
    for (int mt = 0; mt < 4; ++mt) {
        const int node = n0blk + mt * 16 + col;
        if (node >= N) continue;
        const float sum = ls1[0][mt][col] + ls1[1][mt][col] + ls1[2][mt][col] + ls1[3][mt][col];
        const float sq  = ls2[0][mt][col] + ls2[1][mt][col] + ls2[2][mt][col] + ls2[3][mt][col];
        const float mu = sum * (1.f / 128.f);
        const float var = sq * (1.f / 128.f) - mu * mu;
        const float rs = rsqrtf(var + 1e-5f);
        #pragma unroll
        for (int nt = 0; nt < 2; ++nt) {
            const int f0 = w * 32 + nt * 16 + quad * 4;
            const float4 gm = *(const float4*)(gamma + f0);
            const float4 bt = *(const float4*)(beta + f0);
            float4 ov;
            ov.x = (v[mt][nt][0] - mu) * rs * gm.x + bt.x;
            ov.y = (v[mt][nt][1] - mu) * rs * gm.y + bt.y;
            ov.z = (v[mt][nt][2] - mu) * rs * gm.z + bt.z;
            ov.w = (v[mt][nt][3] - mu) * rs * gm.w + bt.w;
            *(float4*)(out + (size_t)node * DIM + f0) = ov;
        }
    }
}

// ---------------------------------------------------------------------------
extern "C" void kernel_launch(void* const* d_in, const int* in_sizes, int n_in,
                              void* d_out, int out_size, void* d_ws, size_t ws_size,
                              hipStream_t stream)
{
    const float* x     = (const float*)d_in[0];
    const int*   eidx  = (const int*)d_in[1];
    const float* Wsrc  = (const float*)d_in[2];
    const float* bsrc  = (const float*)d_in[3];
    const float* Wtgt  = (const float*)d_in[4];
    const float* Wskip = (const float*)d_in[5];
    const float* a0    = (const float*)d_in[6];
    const float* W1    = (const float*)d_in[7];
    const float* b1    = (const float*)d_in[8];
    const float* a1    = (const float*)d_in[9];
    const float* W2    = (const float*)d_in[10];
    const float* b2    = (const float*)d_in[11];
    const float* Wg    = (const float*)d_in[12];
    const float* gamma = (const float*)d_in[13];
    const float* beta  = (const float*)d_in[14];

    const int N = in_sizes[0] / DIM;      // 20000
    const int E = in_sizes[1] / 2;        // 640000
    const int Npad = ((N + 63) / 64) * 64;
    float* out = (float*)d_out;

    char* ws = (char*)d_ws;
    size_t off = 0;
    auto alloc = [&](size_t bytes) -> void* {
        void* p = ws + off;
        off += (bytes + 255) & ~(size_t)255;
        return p;
    };
    unsigned short* msg_src = (unsigned short*)alloc((size_t)N * DIM * 2);
    unsigned short* msg_tgt = (unsigned short*)alloc((size_t)N * DIM * 2);
    float*          skip    = (float*)alloc((size_t)N * DIM * 4);
    float*          gate    = (float*)alloc((size_t)E * 4);
    int*            deg     = (int*)alloc((size_t)N * 4);
    int*            rowptr  = (int*)alloc((size_t)(N + 1) * 4);
    int*            cursor  = (int*)alloc((size_t)N * 4);
    int2*           jip     = (int2*)alloc((size_t)E * 8);
    unsigned short* Wall    = (unsigned short*)alloc((size_t)5 * DIM * DIM * 2);
    float*          w2g     = (float*)alloc((size_t)(DIM + 1) * 4);
    unsigned short* aggh2   = (unsigned short*)alloc((size_t)Npad * DIM * 2);
    unsigned char*  h2buf   = (unsigned char*)alloc((size_t)E * DIM);
    (void)ws_size; (void)n_in; (void)out_size;

    hipMemsetAsync(deg, 0, (size_t)N * 4, stream);

    const int nhist = (E + 255) / 256;
    prep_hist_k<<<nhist + (5 * DIM * DIM) / 256 + 1, 256, 0, stream>>>(
        Wsrc, Wtgt, Wskip, W1, W2, b2, Wg, Wall, w2g, eidx, E, deg);

    scan_k<<<1, 256, 0, stream>>>(deg, rowptr, cursor, N);

    const int nscatter = (E + 255) / 256;
    const int nnode = (N + 31) / 32;
    scatter_node_k<<<nscatter + nnode, 256, 0, stream>>>(
        eidx, E, cursor, jip, nscatter,
        x, Wall, bsrc, msg_src, msg_tgt, skip, N);

    const int ntiles = E / 64;
    const int egrid = ntiles < 1024 ? ntiles : 1024;
    edge_mlp_mfma<<<egrid, 256, 0, stream>>>(jip, ntiles, msg_src, msg_tgt, a0,
                                             Wall + 3 * DIM * DIM, b1, a1,
                                             w2g, h2buf, gate);

    aggregate_h2_k<<<(N + 3) / 4, 256, 0, stream>>>(rowptr, gate, h2buf, aggh2, N);

    node_out_k<<<Npad / 64, 256, 0, stream>>>(aggh2, Wall + 4 * DIM * DIM, b2, skip,
                                              gamma, beta, out, N);
}